// Round 6
// baseline (3687.652 us; speedup 1.0000x reference)
//
#include <hip/hip_runtime.h>
#include <hip/hip_bf16.h>
#include <math.h>

// ---------------------------------------------------------------------------
// GINE x3 + global_add_pool + Bayesian head.
// Round 6: edge_agg phase 2 rebuilt for ILP — 8 features/lane, uint4 gathers,
// 8 independent iterations/wave. Phase 1 (MFMA edge projection) unchanged.
// ---------------------------------------------------------------------------

#define THREADS 256

typedef __attribute__((ext_vector_type(8))) short bf16x8;
typedef __attribute__((ext_vector_type(4))) float f32x4;

__device__ __forceinline__ unsigned short f2bf(float x) {
    __hip_bfloat16 h = __float2bfloat16(x);
    return __builtin_bit_cast(unsigned short, h);
}
__device__ __forceinline__ float bflo(unsigned u) {
    return __builtin_bit_cast(float, u << 16);
}
__device__ __forceinline__ float bfhi(unsigned u) {
    return __builtin_bit_cast(float, u & 0xffff0000u);
}
__device__ __forceinline__ float bf2f(unsigned short u) {
    return __builtin_bit_cast(float, (unsigned)u << 16);
}
__device__ __forceinline__ unsigned pk(float a, float b) {
    return (unsigned)f2bf(a) | ((unsigned)f2bf(b) << 16);
}

// ---------------- CSR build: histogram of dst
__global__ __launch_bounds__(THREADS) void hist_kernel(
    const int* __restrict__ ei, int* __restrict__ deg, int E)
{
    int e = blockIdx.x * THREADS + threadIdx.x;
    if (e < E) atomicAdd(&deg[ei[E + e]], 1);
}

// ---------------- CSR build: single-block exclusive scan -> rowptr[0..n]
__global__ __launch_bounds__(1024) void scan_kernel(
    const int* __restrict__ deg, int* __restrict__ rowptr, int n)
{
    __shared__ int s[1024];
    __shared__ int carry_s;
    const int t = threadIdx.x;
    if (t == 0) carry_s = 0;
    __syncthreads();
    for (int base = 0; base < n; base += 1024) {
        int i = base + t;
        s[t] = (i < n) ? deg[i] : 0;
        __syncthreads();
        for (int off = 1; off < 1024; off <<= 1) {
            int add = (t >= off) ? s[t - off] : 0;
            __syncthreads();
            s[t] += add;
            __syncthreads();
        }
        int incl = s[t];
        int carry = carry_s;
        if (i < n) rowptr[i + 1] = carry + incl;
        __syncthreads();
        if (t == 1023) carry_s = carry + incl;
        __syncthreads();
    }
    if (t == 0) rowptr[0] = 0;
}

// ---------------- CSR build: scatter edge ids into slots (also csr_dst)
__global__ __launch_bounds__(THREADS) void fill_kernel(
    const int* __restrict__ ei, const int* __restrict__ rowptr,
    int* __restrict__ cursor, int* __restrict__ csr_src,
    int* __restrict__ csr_dst, int* __restrict__ csr_eid, int E)
{
    int e = blockIdx.x * THREADS + threadIdx.x;
    if (e >= E) return;
    int s = ei[e], d = ei[E + e];
    int pos  = atomicAdd(&cursor[d], 1);
    int slot = rowptr[d] + pos;
    csr_src[slot] = s;
    csr_dst[slot] = d;
    csr_eid[slot] = e;
}

// ---------------- edge_attr -> bf16 [E][16] in CSR slot order
__global__ __launch_bounds__(THREADS) void easort_kernel(
    const float* __restrict__ edge_attr, const int* __restrict__ csr_eid,
    unsigned short* __restrict__ ea16, int E)
{
    int s = blockIdx.x * THREADS + threadIdx.x;
    if (s >= E) return;
    int eid = csr_eid[s];
    const float4* a = (const float4*)(edge_attr + (size_t)eid * 16);
    float4 a0 = a[0], a1 = a[1], a2 = a[2], a3 = a[3];
    uint4* d = (uint4*)(ea16 + (size_t)s * 16);
    d[0] = make_uint4(pk(a0.x, a0.y), pk(a0.z, a0.w), pk(a1.x, a1.y), pk(a1.z, a1.w));
    d[1] = make_uint4(pk(a2.x, a2.y), pk(a2.z, a2.w), pk(a3.x, a3.y), pk(a3.z, a3.w));
}

// ---------------- x -> bf16 copy
__global__ __launch_bounds__(THREADS) void xprep_kernel(
    const float* __restrict__ x, unsigned short* __restrict__ xbf, int n4)
{
    int i = blockIdx.x * THREADS + threadIdx.x;
    if (i >= n4) return;
    float4 v = ((const float4*)x)[i];
    uint2 p;
    p.x = pk(v.x, v.y);
    p.y = pk(v.z, v.w);
    ((uint2*)xbf)[i] = p;
}

// ---------------- We[16][D] f32 -> Wtp[D][32] bf16 (k 16..31 zero)
__global__ __launch_bounds__(THREADS) void wetrans_kernel(
    const float* __restrict__ We, unsigned short* __restrict__ Wtp, int D)
{
    int f = blockIdx.x * THREADS + threadIdx.x;
    if (f >= D) return;
#pragma unroll
    for (int k = 0; k < 16; k++) Wtp[f * 32 + k] = f2bf(We[k * D + f]);
#pragma unroll
    for (int k = 16; k < 32; k++) Wtp[f * 32 + k] = 0;
}

// ---------------- fused MFMA aggregation:
// phase1: proj[f][e] = ea[e][:16] @ We[:,f]  (MFMA, K padded to 32) -> LDS
// phase2: agg[dst][f] += relu(h[src][f] + proj + be[f])
//         8 feats/lane, uint4 gathers, run-length + f32 atomics
template<int D>
__global__ __launch_bounds__(THREADS) void edge_agg_kernel(
    const unsigned short* __restrict__ hbf,   // [N][D] bf16
    const unsigned short* __restrict__ ea16,  // [E][16] bf16, CSR order
    const int* __restrict__ csr_src,          // [E]
    const int* __restrict__ csr_dst,          // [E] (non-decreasing)
    const unsigned short* __restrict__ Wtp,   // [D][32] bf16, k>=16 zero
    const float* __restrict__ be,             // [D]
    float* __restrict__ agg,                  // [N][D] f32, pre-zeroed
    int E)
{
    constexpr int EPB = (D == 128) ? 128 : 64;   // edges per block
    constexpr int LDF = D + 8;                   // padded LDS stride (mult of 8)
    __shared__ unsigned short msg[EPB * LDF];
    __shared__ int src_s[EPB], dst_s[EPB];

    const int t    = threadIdx.x;
    const int e0   = blockIdx.x * EPB;
    const int lane = t & 63, wid = t >> 6;
    const int l15  = lane & 15, lgr = lane >> 4;

    // stage src/dst for phase 2
    for (int i = t; i < EPB; i += THREADS) {
        int e = e0 + i;
        src_s[i] = (e < E) ? csr_src[e] : 0;
        dst_s[i] = (e < E) ? csr_dst[e] : 0;
    }

    // ---- phase 1: MFMA projection, C[feature][edge]
    const int fb = (D == 128) ? (wid & 1) * 64 : wid * 64;   // feature base
    const int eb = (D == 128) ? (wid >> 1) * 64 : 0;         // edge base

    bf16x8 af[4];
#pragma unroll
    for (int mf = 0; mf < 4; mf++)
        af[mf] = *(const bf16x8*)(Wtp + (size_t)(fb + mf * 16 + l15) * 32 + lgr * 8);

    f32x4 acc[4][4];
#pragma unroll
    for (int a = 0; a < 4; a++)
#pragma unroll
        for (int b = 0; b < 4; b++) acc[a][b] = (f32x4){0.f, 0.f, 0.f, 0.f};

#pragma unroll
    for (int nf = 0; nf < 4; nf++) {
        int er = e0 + eb + nf * 16 + l15;
        bf16x8 bv = (bf16x8){0, 0, 0, 0, 0, 0, 0, 0};
        if (lgr < 2 && er < E)
            bv = *(const bf16x8*)(ea16 + (size_t)er * 16 + lgr * 8);
#pragma unroll
        for (int mf = 0; mf < 4; mf++)
            acc[mf][nf] = __builtin_amdgcn_mfma_f32_16x16x32_bf16(
                af[mf], bv, acc[mf][nf], 0, 0, 0);
    }

    // write proj tile to LDS (bf16)
#pragma unroll
    for (int nf = 0; nf < 4; nf++) {
        int edge = eb + nf * 16 + l15;
#pragma unroll
        for (int mf = 0; mf < 4; mf++) {
            int fpos = fb + mf * 16 + lgr * 4;
            f32x4 v = acc[mf][nf];
            uint2 p;
            p.x = pk(v[0], v[1]);
            p.y = pk(v[2], v[3]);
            *(uint2*)(&msg[edge * LDF + fpos]) = p;
        }
    }
    __syncthreads();

    // ---- phase 2: 8 feats/lane wide-load gather + run-length segment sum
    constexpr int LPE  = D / 8;          // lanes per edge (16 or 32)
    constexpr int EPW  = 64 / LPE;       // edges per wave-iteration (4 or 2)
    constexpr int CPW  = EPB / 4;        // edges per wave chunk
    constexpr int NIT  = CPW / EPW;      // iterations (= 8)

    const int se   = lane / LPE;                 // sub-edge in group
    const int fb8  = (lane % LPE) * 8;           // feature base (8 feats)
    const int lim  = (E - e0 < EPB) ? (E - e0) : EPB;

    float be8[8];
    {
        float4 b0 = *(const float4*)(be + fb8);
        float4 b1 = *(const float4*)(be + fb8 + 4);
        be8[0]=b0.x; be8[1]=b0.y; be8[2]=b0.z; be8[3]=b0.w;
        be8[4]=b1.x; be8[5]=b1.y; be8[6]=b1.z; be8[7]=b1.w;
    }

    float a8[8];
#pragma unroll
    for (int j = 0; j < 8; j++) a8[j] = 0.f;
    int cur = -1;

#pragma unroll
    for (int i = 0; i < NIT; ++i) {
        int e = wid * CPW + i * EPW + se;
        if (e < lim) {
            int d = dst_s[e];
            if (d != cur) {
                if (cur >= 0) {
                    float* ap = agg + (size_t)cur * D + fb8;
#pragma unroll
                    for (int j = 0; j < 8; j++) { atomicAdd(ap + j, a8[j]); a8[j] = 0.f; }
                }
                cur = d;
            }
            int src = src_s[e];
            uint4 hv = *(const uint4*)(hbf + (size_t)src * D + fb8);
            uint4 pv = *(const uint4*)(&msg[e * LDF + fb8]);
            a8[0] += fmaxf(bflo(hv.x) + bflo(pv.x) + be8[0], 0.f);
            a8[1] += fmaxf(bfhi(hv.x) + bfhi(pv.x) + be8[1], 0.f);
            a8[2] += fmaxf(bflo(hv.y) + bflo(pv.y) + be8[2], 0.f);
            a8[3] += fmaxf(bfhi(hv.y) + bfhi(pv.y) + be8[3], 0.f);
            a8[4] += fmaxf(bflo(hv.z) + bflo(pv.z) + be8[4], 0.f);
            a8[5] += fmaxf(bfhi(hv.z) + bfhi(pv.z) + be8[5], 0.f);
            a8[6] += fmaxf(bflo(hv.w) + bflo(pv.w) + be8[6], 0.f);
            a8[7] += fmaxf(bfhi(hv.w) + bfhi(pv.w) + be8[7], 0.f);
        }
    }
    if (cur >= 0) {
        float* ap = agg + (size_t)cur * D + fb8;
#pragma unroll
        for (int j = 0; j < 8; j++) atomicAdd(ap + j, a8[j]);
    }
}

// ---------------- W transpose + bf16 convert: W[K,256] f32 -> Wt[256,K] bf16
__global__ __launch_bounds__(THREADS) void wtrans_kernel(
    const float* __restrict__ W, unsigned short* __restrict__ Wt, int K)
{
    __shared__ float tile[32][33];
    const int kb = blockIdx.x * 32, nb = blockIdx.y * 32;
    const int tx = threadIdx.x & 31, ty = threadIdx.x >> 5;
#pragma unroll
    for (int i = ty; i < 32; i += 8)
        tile[i][tx] = W[(size_t)(kb + i) * 256 + nb + tx];
    __syncthreads();
#pragma unroll
    for (int i = ty; i < 32; i += 8)
        Wt[(size_t)(nb + i) * K + kb + tx] = f2bf(tile[tx][i]);
}

// ---------------- MFMA node-MLP GEMM (bf16 h in, bf16 out):
// MODE 0: A = (1+eps)*hin + agg(f32)    MODE 1: A = hin
template<int K, int MODE>
__global__ __launch_bounds__(THREADS) void mfma_mlp_kernel(
    const unsigned short* __restrict__ hin,   // [nrows, K] bf16
    const float* __restrict__ agg,            // [nrows, K] f32 (MODE 0)
    const unsigned short* __restrict__ Wt,    // [256, K] bf16
    const float* __restrict__ bias,           // [256]
    const float* __restrict__ epsp,           // [1] (MODE 0)
    unsigned short* __restrict__ out,         // [nrows, 256] bf16
    int nrows)
{
    constexpr int BM = 128, BK = 64;
    constexpr int LDR = BK + 8;
    __shared__ short As[BM * LDR];
    __shared__ short Bs[128 * LDR];

    const int t    = threadIdx.x;
    const int lane = t & 63;
    const int wid  = t >> 6;
    const int wm   = wid >> 1, wn = wid & 1;
    const int l15  = lane & 15, lgr = lane >> 4;

    const int r0 = blockIdx.x * BM;
    const int n0 = blockIdx.y * 128;

    float scale = 1.0f;
    if (MODE == 0) scale = 1.0f + epsp[0];

    f32x4 acc[4][4];
#pragma unroll
    for (int a = 0; a < 4; a++)
#pragma unroll
        for (int b = 0; b < 4; b++) acc[a][b] = (f32x4){0.f, 0.f, 0.f, 0.f};

    for (int k0 = 0; k0 < K; k0 += BK) {
#pragma unroll
        for (int c = 0; c < 4; c++) {
            int idx = t + c * THREADS;
            int r   = idx >> 3;
            int kq  = idx & 7;
            int row = r0 + r;
            uint4 o = make_uint4(0, 0, 0, 0);
            if (row < nrows) {
                size_t g = (size_t)row * K + k0 + kq * 8;
                uint4 hv = *(const uint4*)(hin + g);
                if (MODE == 0) {
                    float4 a0 = *(const float4*)(agg + g);
                    float4 a1 = *(const float4*)(agg + g + 4);
                    o.x = pk(scale * bflo(hv.x) + a0.x, scale * bfhi(hv.x) + a0.y);
                    o.y = pk(scale * bflo(hv.y) + a0.z, scale * bfhi(hv.y) + a0.w);
                    o.z = pk(scale * bflo(hv.z) + a1.x, scale * bfhi(hv.z) + a1.y);
                    o.w = pk(scale * bflo(hv.w) + a1.z, scale * bfhi(hv.w) + a1.w);
                } else {
                    o = hv;
                }
            }
            *(uint4*)(&As[r * LDR + kq * 8]) = o;
        }
#pragma unroll
        for (int c = 0; c < 4; c++) {
            int idx = t + c * THREADS;
            int n   = idx >> 3;
            int kq  = idx & 7;
            uint4 w = *(const uint4*)(Wt + (size_t)(n0 + n) * K + k0 + kq * 8);
            *(uint4*)(&Bs[n * LDR + kq * 8]) = w;
        }
        __syncthreads();

#pragma unroll
        for (int ks = 0; ks < 2; ks++) {
            bf16x8 af[4], bfr[4];
#pragma unroll
            for (int mf = 0; mf < 4; mf++)
                af[mf] = *(const bf16x8*)(&As[(wm * 64 + mf * 16 + l15) * LDR + ks * 32 + lgr * 8]);
#pragma unroll
            for (int nf = 0; nf < 4; nf++)
                bfr[nf] = *(const bf16x8*)(&Bs[(wn * 64 + nf * 16 + l15) * LDR + ks * 32 + lgr * 8]);
#pragma unroll
            for (int mf = 0; mf < 4; mf++)
#pragma unroll
                for (int nf = 0; nf < 4; nf++)
                    acc[mf][nf] = __builtin_amdgcn_mfma_f32_16x16x32_bf16(
                        af[mf], bfr[nf], acc[mf][nf], 0, 0, 0);
        }
        __syncthreads();
    }

#pragma unroll
    for (int nf = 0; nf < 4; nf++) {
        int col = n0 + wn * 64 + nf * 16 + l15;
        float bcol = bias[col];
#pragma unroll
        for (int mf = 0; mf < 4; mf++) {
            f32x4 v = acc[mf][nf];
#pragma unroll
            for (int r = 0; r < 4; r++) {
                int row = r0 + wm * 64 + mf * 16 + lgr * 4 + r;
                if (row < nrows)
                    out[(size_t)row * 256 + col] = f2bf(fmaxf(v[r] + bcol, 0.f));
            }
        }
    }
}

// ---------------- global add pool
__global__ __launch_bounds__(THREADS) void pool_kernel(
    const unsigned short* __restrict__ hbf,  // [N, 256] bf16
    const int*   __restrict__ batch,         // [N]
    float*       __restrict__ hg,            // [G, 256] f32
    int nnodes)
{
    constexpr int CH = 64;
    __shared__ int b_s[CH];
    const int t  = threadIdx.x;
    const int v0 = blockIdx.x * CH;
    int cnt = nnodes - v0;
    if (cnt > CH) cnt = CH;
    if (cnt <= 0) return;
    if (t < cnt) b_s[t] = batch[v0 + t];
    __syncthreads();

    int curb  = b_s[0];
    float acc = 0.f;
    for (int v = 0; v < cnt; v++) {
        int b = b_s[v];
        if (b != curb) {
            atomicAdd(&hg[(size_t)curb * 256 + t], acc);
            acc = 0.f; curb = b;
        }
        acc += bf2f(hbf[(size_t)(v0 + v) * 256 + t]);
    }
    atomicAdd(&hg[(size_t)curb * 256 + t], acc);
}

// ---------------- Bayesian weight materialization
__global__ void wprep_kernel(const float* __restrict__ mu,
                             const float* __restrict__ ls,
                             const float* __restrict__ eps,
                             float* __restrict__ w, int n)
{
    int i = blockIdx.x * THREADS + threadIdx.x;
    if (i < n) w[i] = mu[i] + expf(ls[i]) * eps[i];
}

// ---------------- head
__global__ __launch_bounds__(THREADS) void head_kernel(
    const float* __restrict__ hg,
    const float* __restrict__ w1,
    const float* __restrict__ h1_bmu, const float* __restrict__ h1_bls,
    const float* __restrict__ eps_b1,
    const float* __restrict__ h2_wmu, const float* __restrict__ h2_wls,
    const float* __restrict__ eps_w2,
    const float* __restrict__ h2_bmu, const float* __restrict__ h2_bls,
    const float* __restrict__ eps_b2,
    float* __restrict__ out)
{
    __shared__ float x_s[256];
    __shared__ float red[256];
    const int t = threadIdx.x;
    const int g = blockIdx.x;

    x_s[t] = hg[(size_t)g * 256 + t];
    __syncthreads();

    float acc = h1_bmu[t] + expf(h1_bls[t]) * eps_b1[t];
    for (int kk = 0; kk < 256; kk++) acc += x_s[kk] * w1[kk * 256 + t];
    float h1v = acc / (1.f + expf(-acc));

    float w2a = h2_wmu[t * 2 + 0] + expf(h2_wls[t * 2 + 0]) * eps_w2[t * 2 + 0];
    float w2b = h2_wmu[t * 2 + 1] + expf(h2_wls[t * 2 + 1]) * eps_w2[t * 2 + 1];

    red[t] = h1v * w2a;
    __syncthreads();
    for (int s = 128; s > 0; s >>= 1) {
        if (t < s) red[t] += red[t + s];
        __syncthreads();
    }
    if (t == 0) out[(size_t)g * 2 + 0] = red[0] + h2_bmu[0] + expf(h2_bls[0]) * eps_b2[0];
    __syncthreads();

    red[t] = h1v * w2b;
    __syncthreads();
    for (int s = 128; s > 0; s >>= 1) {
        if (t < s) red[t] += red[t + s];
        __syncthreads();
    }
    if (t == 0) out[(size_t)g * 2 + 1] = red[0] + h2_bmu[1] + expf(h2_bls[1]) * eps_b2[1];
}

// ---------------------------------------------------------------------------
extern "C" void kernel_launch(void* const* d_in, const int* in_sizes, int n_in,
                              void* d_out, int out_size, void* d_ws, size_t ws_size,
                              hipStream_t stream)
{
    const float* x         = (const float*)d_in[0];
    const float* edge_attr = (const float*)d_in[1];
    const int*   ei        = (const int*)d_in[2];
    const int*   batch     = (const int*)d_in[3];

    const float* We[3]  = { (const float*)d_in[4],  (const float*)d_in[11], (const float*)d_in[18] };
    const float* be[3]  = { (const float*)d_in[5],  (const float*)d_in[12], (const float*)d_in[19] };
    const float* W1[3]  = { (const float*)d_in[6],  (const float*)d_in[13], (const float*)d_in[20] };
    const float* b1[3]  = { (const float*)d_in[7],  (const float*)d_in[14], (const float*)d_in[21] };
    const float* W2[3]  = { (const float*)d_in[8],  (const float*)d_in[15], (const float*)d_in[22] };
    const float* b2[3]  = { (const float*)d_in[9],  (const float*)d_in[16], (const float*)d_in[23] };
    const float* epsl[3]= { (const float*)d_in[10], (const float*)d_in[17], (const float*)d_in[24] };

    const float* h1_wmu = (const float*)d_in[25];
    const float* h1_wls = (const float*)d_in[26];
    const float* h1_bmu = (const float*)d_in[27];
    const float* h1_bls = (const float*)d_in[28];
    const float* h2_wmu = (const float*)d_in[29];
    const float* h2_wls = (const float*)d_in[30];
    const float* h2_bmu = (const float*)d_in[31];
    const float* h2_bls = (const float*)d_in[32];
    const float* eps_w1 = (const float*)d_in[33];
    const float* eps_b1 = (const float*)d_in[34];
    const float* eps_w2 = (const float*)d_in[35];
    const float* eps_b2 = (const float*)d_in[36];

    const int N = in_sizes[0] / 128;
    const int E = in_sizes[1] / 16;
    const int G = out_size / 2;

    // ---- carve workspace (256B aligned chunks)
    uintptr_t p = (uintptr_t)d_ws;
    auto carve = [&](size_t bytes) -> void* {
        void* r = (void*)p;
        p = (p + bytes + 255) & ~(uintptr_t)255;
        return r;
    };
    float* hg      = (float*)carve((size_t)G * 256 * 4);
    float* w1buf   = (float*)carve(256 * 256 * 4);
    float* aggf    = (float*)carve((size_t)N * 256 * 4);
    int*   rowptr  = (int*)carve((size_t)(N + 1) * 4);
    int*   cursor  = (int*)carve((size_t)N * 4);
    int*   csr_src = (int*)carve((size_t)E * 4);
    int*   csr_dst = (int*)carve((size_t)E * 4);
    int*   csr_eid = (int*)carve((size_t)E * 4);
    unsigned short* ea16  = (unsigned short*)carve((size_t)E * 16 * 2);
    unsigned short* hbf   = (unsigned short*)carve((size_t)N * 256 * 2);
    unsigned short* tmpbf = (unsigned short*)carve((size_t)N * 256 * 2);
    unsigned short* xbf   = (unsigned short*)carve((size_t)N * 128 * 2);
    unsigned short* wep[3];
    wep[0] = (unsigned short*)carve(128 * 32 * 2);
    wep[1] = (unsigned short*)carve(256 * 32 * 2);
    wep[2] = (unsigned short*)carve(256 * 32 * 2);
    unsigned short* wt1[3], *wt2[3];
    wt1[0] = (unsigned short*)carve(256 * 128 * 2);
    for (int l = 0; l < 3; l++) {
        if (l) wt1[l] = (unsigned short*)carve(256 * 256 * 2);
        wt2[l] = (unsigned short*)carve(256 * 256 * 2);
    }

    const int eblocks     = (E + THREADS - 1) / THREADS;
    const int pool_blocks = (N + 63) / 64;
    const dim3 ggrid((N + 127) / 128, 2);

    float* out = (float*)d_out;

    // ---- build CSR once
    hipMemsetAsync(cursor, 0, (size_t)N * sizeof(int), stream);
    hist_kernel<<<eblocks, THREADS, 0, stream>>>(ei, cursor, E);
    scan_kernel<<<1, 1024, 0, stream>>>(cursor, rowptr, N);
    hipMemsetAsync(cursor, 0, (size_t)N * sizeof(int), stream);
    fill_kernel<<<eblocks, THREADS, 0, stream>>>(ei, rowptr, cursor, csr_src, csr_dst, csr_eid, E);
    easort_kernel<<<eblocks, THREADS, 0, stream>>>(edge_attr, csr_eid, ea16, E);
    xprep_kernel<<<(N * 32 + THREADS - 1) / THREADS, THREADS, 0, stream>>>(x, xbf, N * 32);

    // ---- weight prep
    wetrans_kernel<<<1, 128, 0, stream>>>(We[0], wep[0], 128);
    wetrans_kernel<<<1, 256, 0, stream>>>(We[1], wep[1], 256);
    wetrans_kernel<<<1, 256, 0, stream>>>(We[2], wep[2], 256);
    wtrans_kernel<<<dim3(4, 8), THREADS, 0, stream>>>(W1[0], wt1[0], 128);
    wtrans_kernel<<<dim3(8, 8), THREADS, 0, stream>>>(W2[0], wt2[0], 256);
    for (int l = 1; l < 3; l++) {
        wtrans_kernel<<<dim3(8, 8), THREADS, 0, stream>>>(W1[l], wt1[l], 256);
        wtrans_kernel<<<dim3(8, 8), THREADS, 0, stream>>>(W2[l], wt2[l], 256);
    }

    // ---- layer 0 (d = 128, h = xbf)
    hipMemsetAsync(aggf, 0, (size_t)N * 128 * sizeof(float), stream);
    edge_agg_kernel<128><<<(E + 127) / 128, THREADS, 0, stream>>>(
        xbf, ea16, csr_src, csr_dst, wep[0], be[0], aggf, E);
    mfma_mlp_kernel<128, 0><<<ggrid, THREADS, 0, stream>>>(
        xbf, aggf, wt1[0], b1[0], epsl[0], tmpbf, N);
    mfma_mlp_kernel<256, 1><<<ggrid, THREADS, 0, stream>>>(
        tmpbf, nullptr, wt2[0], b2[0], nullptr, hbf, N);

    // ---- layers 1, 2 (d = 256)
    for (int l = 1; l < 3; l++) {
        hipMemsetAsync(aggf, 0, (size_t)N * 256 * sizeof(float), stream);
        edge_agg_kernel<256><<<(E + 63) / 64, THREADS, 0, stream>>>(
            hbf, ea16, csr_src, csr_dst, wep[l], be[l], aggf, E);
        mfma_mlp_kernel<256, 0><<<ggrid, THREADS, 0, stream>>>(
            hbf, aggf, wt1[l], b1[l], epsl[l], tmpbf, N);
        mfma_mlp_kernel<256, 1><<<ggrid, THREADS, 0, stream>>>(
            tmpbf, nullptr, wt2[l], b2[l], nullptr, hbf, N);
    }

    // ---- global add pool -> hg
    hipMemsetAsync(hg, 0, (size_t)G * 256 * sizeof(float), stream);
    pool_kernel<<<pool_blocks, THREADS, 0, stream>>>(hbf, batch, hg, N);

    // ---- Bayesian head
    wprep_kernel<<<(256 * 256 + THREADS - 1) / THREADS, THREADS, 0, stream>>>(
        h1_wmu, h1_wls, eps_w1, w1buf, 256 * 256);
    head_kernel<<<G, THREADS, 0, stream>>>(
        hg, w1buf, h1_bmu, h1_bls, eps_b1,
        h2_wmu, h2_wls, eps_w2, h2_bmu, h2_bls, eps_b2, out);
}

// Round 7
// 827.043 us; speedup vs baseline: 4.4588x; 4.4588x over previous
//
#include <hip/hip_runtime.h>
#include <hip/hip_bf16.h>
#include <math.h>

// ---------------------------------------------------------------------------
// GINE x3 + global_add_pool + Bayesian head.
// Round 7: edge_agg = MFMA projection (bias folded into C-init) + phase-2 with
// CONSECUTIVE 16-edge windows/thread, 2 feats/thread (uint loads), EPB=32
// (17KB LDS -> ~100% occupancy). R6's stride-interleave reverted.
// ---------------------------------------------------------------------------

#define THREADS 256

typedef __attribute__((ext_vector_type(8))) short bf16x8;
typedef __attribute__((ext_vector_type(4))) float f32x4;

__device__ __forceinline__ unsigned short f2bf(float x) {
    __hip_bfloat16 h = __float2bfloat16(x);
    return __builtin_bit_cast(unsigned short, h);
}
__device__ __forceinline__ float bflo(unsigned u) {
    return __builtin_bit_cast(float, u << 16);
}
__device__ __forceinline__ float bfhi(unsigned u) {
    return __builtin_bit_cast(float, u & 0xffff0000u);
}
__device__ __forceinline__ float bf2f(unsigned short u) {
    return __builtin_bit_cast(float, (unsigned)u << 16);
}
__device__ __forceinline__ unsigned pk(float a, float b) {
    return (unsigned)f2bf(a) | ((unsigned)f2bf(b) << 16);
}

// ---------------- CSR build: histogram of dst
__global__ __launch_bounds__(THREADS) void hist_kernel(
    const int* __restrict__ ei, int* __restrict__ deg, int E)
{
    int e = blockIdx.x * THREADS + threadIdx.x;
    if (e < E) atomicAdd(&deg[ei[E + e]], 1);
}

// ---------------- CSR build: single-block exclusive scan -> rowptr[0..n]
__global__ __launch_bounds__(1024) void scan_kernel(
    const int* __restrict__ deg, int* __restrict__ rowptr, int n)
{
    __shared__ int s[1024];
    __shared__ int carry_s;
    const int t = threadIdx.x;
    if (t == 0) carry_s = 0;
    __syncthreads();
    for (int base = 0; base < n; base += 1024) {
        int i = base + t;
        s[t] = (i < n) ? deg[i] : 0;
        __syncthreads();
        for (int off = 1; off < 1024; off <<= 1) {
            int add = (t >= off) ? s[t - off] : 0;
            __syncthreads();
            s[t] += add;
            __syncthreads();
        }
        int incl = s[t];
        int carry = carry_s;
        if (i < n) rowptr[i + 1] = carry + incl;
        __syncthreads();
        if (t == 1023) carry_s = carry + incl;
        __syncthreads();
    }
    if (t == 0) rowptr[0] = 0;
}

// ---------------- CSR build: scatter edge ids into slots (also csr_dst)
__global__ __launch_bounds__(THREADS) void fill_kernel(
    const int* __restrict__ ei, const int* __restrict__ rowptr,
    int* __restrict__ cursor, int* __restrict__ csr_src,
    int* __restrict__ csr_dst, int* __restrict__ csr_eid, int E)
{
    int e = blockIdx.x * THREADS + threadIdx.x;
    if (e >= E) return;
    int s = ei[e], d = ei[E + e];
    int pos  = atomicAdd(&cursor[d], 1);
    int slot = rowptr[d] + pos;
    csr_src[slot] = s;
    csr_dst[slot] = d;
    csr_eid[slot] = e;
}

// ---------------- edge_attr -> bf16 [E][16] in CSR slot order
__global__ __launch_bounds__(THREADS) void easort_kernel(
    const float* __restrict__ edge_attr, const int* __restrict__ csr_eid,
    unsigned short* __restrict__ ea16, int E)
{
    int s = blockIdx.x * THREADS + threadIdx.x;
    if (s >= E) return;
    int eid = csr_eid[s];
    const float4* a = (const float4*)(edge_attr + (size_t)eid * 16);
    float4 a0 = a[0], a1 = a[1], a2 = a[2], a3 = a[3];
    uint4* d = (uint4*)(ea16 + (size_t)s * 16);
    d[0] = make_uint4(pk(a0.x, a0.y), pk(a0.z, a0.w), pk(a1.x, a1.y), pk(a1.z, a1.w));
    d[1] = make_uint4(pk(a2.x, a2.y), pk(a2.z, a2.w), pk(a3.x, a3.y), pk(a3.z, a3.w));
}

// ---------------- x -> bf16 copy
__global__ __launch_bounds__(THREADS) void xprep_kernel(
    const float* __restrict__ x, unsigned short* __restrict__ xbf, int n4)
{
    int i = blockIdx.x * THREADS + threadIdx.x;
    if (i >= n4) return;
    float4 v = ((const float4*)x)[i];
    uint2 p;
    p.x = pk(v.x, v.y);
    p.y = pk(v.z, v.w);
    ((uint2*)xbf)[i] = p;
}

// ---------------- We[16][D] f32 -> Wtp[D][32] bf16 (k 16..31 zero)
__global__ __launch_bounds__(THREADS) void wetrans_kernel(
    const float* __restrict__ We, unsigned short* __restrict__ Wtp, int D)
{
    int f = blockIdx.x * THREADS + threadIdx.x;
    if (f >= D) return;
#pragma unroll
    for (int k = 0; k < 16; k++) Wtp[f * 32 + k] = f2bf(We[k * D + f]);
#pragma unroll
    for (int k = 16; k < 32; k++) Wtp[f * 32 + k] = 0;
}

// ---------------- fused MFMA aggregation:
// phase1: msg[f][e] = ea[e][:16] @ We[:,f] + be[f]  (MFMA, bias in C-init)
// phase2: agg[dst][f] += relu(h[src][f] + msg)  2 feats/thread, 16-edge
//         consecutive windows, run-length flush with coalesced f32 atomics
template<int D>
__global__ __launch_bounds__(THREADS) void edge_agg_kernel(
    const unsigned short* __restrict__ hbf,   // [N][D] bf16
    const unsigned short* __restrict__ ea16,  // [E][16] bf16, CSR order
    const int* __restrict__ csr_src,          // [E]
    const int* __restrict__ csr_dst,          // [E] (non-decreasing)
    const unsigned short* __restrict__ Wtp,   // [D][32] bf16, k>=16 zero
    const float* __restrict__ be,             // [D]
    float* __restrict__ agg,                  // [N][D] f32, pre-zeroed
    int E)
{
    constexpr int EPB = (D == 128) ? 64 : 32;    // edges per block
    constexpr int LDF = D + 8;                   // padded LDS stride (shorts)
    __shared__ unsigned short msg[EPB * LDF];
    __shared__ int src_s[EPB], dst_s[EPB];

    const int t    = threadIdx.x;
    const int e0   = blockIdx.x * EPB;
    const int lane = t & 63, wid = t >> 6;
    const int l15  = lane & 15, lgr = lane >> 4;

    // stage src/dst for phase 2 (tail zero-padded: safe fake edges)
    for (int i = t; i < EPB; i += THREADS) {
        int e = e0 + i;
        src_s[i] = (e < E) ? csr_src[e] : 0;
        dst_s[i] = (e < E) ? csr_dst[e] : 0;
    }

    // ---- phase 1: MFMA projection, C[feature][edge], bias in C-init
    const int fb = (D == 128) ? (wid & 1) * 64 : wid * 64;   // feature base
    const int eb = (D == 128) ? (wid >> 1) * 32 : 0;         // edge base

    bf16x8 af[4];
#pragma unroll
    for (int mf = 0; mf < 4; mf++)
        af[mf] = *(const bf16x8*)(Wtp + (size_t)(fb + mf * 16 + l15) * 32 + lgr * 8);

    f32x4 acc[4][2];
#pragma unroll
    for (int mf = 0; mf < 4; mf++) {
        int fpos = fb + mf * 16 + lgr * 4;
        float4 bv4 = *(const float4*)(be + fpos);
        f32x4 binit = (f32x4){bv4.x, bv4.y, bv4.z, bv4.w};
        acc[mf][0] = binit;
        acc[mf][1] = binit;
    }

#pragma unroll
    for (int nf = 0; nf < 2; nf++) {
        int er = e0 + eb + nf * 16 + l15;
        bf16x8 bv = (bf16x8){0, 0, 0, 0, 0, 0, 0, 0};
        if (lgr < 2 && er < E)
            bv = *(const bf16x8*)(ea16 + (size_t)er * 16 + lgr * 8);
#pragma unroll
        for (int mf = 0; mf < 4; mf++)
            acc[mf][nf] = __builtin_amdgcn_mfma_f32_16x16x32_bf16(
                af[mf], bv, acc[mf][nf], 0, 0, 0);
    }

    // write msg tile to LDS (bf16)
#pragma unroll
    for (int nf = 0; nf < 2; nf++) {
        int edge = eb + nf * 16 + l15;
#pragma unroll
        for (int mf = 0; mf < 4; mf++) {
            int fpos = fb + mf * 16 + lgr * 4;
            f32x4 v = acc[mf][nf];
            uint2 p;
            p.x = pk(v[0], v[1]);
            p.y = pk(v[2], v[3]);
            *(uint2*)(&msg[edge * LDF + fpos]) = p;
        }
    }
    __syncthreads();

    // ---- phase 2: 2 feats/thread, consecutive 16-edge window, run-length
    constexpr int LPF = D / 2;             // lane-pairs covering all features
    const int f2  = (t & (LPF - 1)) * 2;   // feature pair
    const int win = t / LPF;               // window index (2 or 4 per block)

    float a0 = 0.f, a1 = 0.f;
    int cur = -1;

#pragma unroll
    for (int i = 0; i < 16; ++i) {
        int el = win * 16 + i;
        int e  = e0 + el;
        int d   = dst_s[el];
        int src = src_s[el];
        unsigned hv = *(const unsigned*)(hbf + (size_t)src * D + f2);
        unsigned pv = *(const unsigned*)(&msg[el * LDF + f2]);
        float m0 = fmaxf(bflo(hv) + bflo(pv), 0.f);
        float m1 = fmaxf(bfhi(hv) + bfhi(pv), 0.f);
        if (d != cur) {
            if (cur >= 0) {
                atomicAdd(&agg[(size_t)cur * D + f2],     a0);
                atomicAdd(&agg[(size_t)cur * D + f2 + 1], a1);
                a0 = 0.f; a1 = 0.f;
            }
            cur = d;
        }
        bool ok = (e < E);
        a0 += ok ? m0 : 0.f;
        a1 += ok ? m1 : 0.f;
    }
    if (cur >= 0) {
        atomicAdd(&agg[(size_t)cur * D + f2],     a0);
        atomicAdd(&agg[(size_t)cur * D + f2 + 1], a1);
    }
}

// ---------------- W transpose + bf16 convert: W[K,256] f32 -> Wt[256,K] bf16
__global__ __launch_bounds__(THREADS) void wtrans_kernel(
    const float* __restrict__ W, unsigned short* __restrict__ Wt, int K)
{
    __shared__ float tile[32][33];
    const int kb = blockIdx.x * 32, nb = blockIdx.y * 32;
    const int tx = threadIdx.x & 31, ty = threadIdx.x >> 5;
#pragma unroll
    for (int i = ty; i < 32; i += 8)
        tile[i][tx] = W[(size_t)(kb + i) * 256 + nb + tx];
    __syncthreads();
#pragma unroll
    for (int i = ty; i < 32; i += 8)
        Wt[(size_t)(nb + i) * K + kb + tx] = f2bf(tile[tx][i]);
}

// ---------------- MFMA node-MLP GEMM (bf16 h in, bf16 out):
// MODE 0: A = (1+eps)*hin + agg(f32)    MODE 1: A = hin
template<int K, int MODE>
__global__ __launch_bounds__(THREADS) void mfma_mlp_kernel(
    const unsigned short* __restrict__ hin,   // [nrows, K] bf16
    const float* __restrict__ agg,            // [nrows, K] f32 (MODE 0)
    const unsigned short* __restrict__ Wt,    // [256, K] bf16
    const float* __restrict__ bias,           // [256]
    const float* __restrict__ epsp,           // [1] (MODE 0)
    unsigned short* __restrict__ out,         // [nrows, 256] bf16
    int nrows)
{
    constexpr int BM = 128, BK = 64;
    constexpr int LDR = BK + 8;
    __shared__ short As[BM * LDR];
    __shared__ short Bs[128 * LDR];

    const int t    = threadIdx.x;
    const int lane = t & 63;
    const int wid  = t >> 6;
    const int wm   = wid >> 1, wn = wid & 1;
    const int l15  = lane & 15, lgr = lane >> 4;

    const int r0 = blockIdx.x * BM;
    const int n0 = blockIdx.y * 128;

    float scale = 1.0f;
    if (MODE == 0) scale = 1.0f + epsp[0];

    f32x4 acc[4][4];
#pragma unroll
    for (int a = 0; a < 4; a++)
#pragma unroll
        for (int b = 0; b < 4; b++) acc[a][b] = (f32x4){0.f, 0.f, 0.f, 0.f};

    for (int k0 = 0; k0 < K; k0 += BK) {
#pragma unroll
        for (int c = 0; c < 4; c++) {
            int idx = t + c * THREADS;
            int r   = idx >> 3;
            int kq  = idx & 7;
            int row = r0 + r;
            uint4 o = make_uint4(0, 0, 0, 0);
            if (row < nrows) {
                size_t g = (size_t)row * K + k0 + kq * 8;
                uint4 hv = *(const uint4*)(hin + g);
                if (MODE == 0) {
                    float4 a0 = *(const float4*)(agg + g);
                    float4 a1 = *(const float4*)(agg + g + 4);
                    o.x = pk(scale * bflo(hv.x) + a0.x, scale * bfhi(hv.x) + a0.y);
                    o.y = pk(scale * bflo(hv.y) + a0.z, scale * bfhi(hv.y) + a0.w);
                    o.z = pk(scale * bflo(hv.z) + a1.x, scale * bfhi(hv.z) + a1.y);
                    o.w = pk(scale * bflo(hv.w) + a1.z, scale * bfhi(hv.w) + a1.w);
                } else {
                    o = hv;
                }
            }
            *(uint4*)(&As[r * LDR + kq * 8]) = o;
        }
#pragma unroll
        for (int c = 0; c < 4; c++) {
            int idx = t + c * THREADS;
            int n   = idx >> 3;
            int kq  = idx & 7;
            uint4 w = *(const uint4*)(Wt + (size_t)(n0 + n) * K + k0 + kq * 8);
            *(uint4*)(&Bs[n * LDR + kq * 8]) = w;
        }
        __syncthreads();

#pragma unroll
        for (int ks = 0; ks < 2; ks++) {
            bf16x8 af[4], bfr[4];
#pragma unroll
            for (int mf = 0; mf < 4; mf++)
                af[mf] = *(const bf16x8*)(&As[(wm * 64 + mf * 16 + l15) * LDR + ks * 32 + lgr * 8]);
#pragma unroll
            for (int nf = 0; nf < 4; nf++)
                bfr[nf] = *(const bf16x8*)(&Bs[(wn * 64 + nf * 16 + l15) * LDR + ks * 32 + lgr * 8]);
#pragma unroll
            for (int mf = 0; mf < 4; mf++)
#pragma unroll
                for (int nf = 0; nf < 4; nf++)
                    acc[mf][nf] = __builtin_amdgcn_mfma_f32_16x16x32_bf16(
                        af[mf], bfr[nf], acc[mf][nf], 0, 0, 0);
        }
        __syncthreads();
    }

#pragma unroll
    for (int nf = 0; nf < 4; nf++) {
        int col = n0 + wn * 64 + nf * 16 + l15;
        float bcol = bias[col];
#pragma unroll
        for (int mf = 0; mf < 4; mf++) {
            f32x4 v = acc[mf][nf];
#pragma unroll
            for (int r = 0; r < 4; r++) {
                int row = r0 + wm * 64 + mf * 16 + lgr * 4 + r;
                if (row < nrows)
                    out[(size_t)row * 256 + col] = f2bf(fmaxf(v[r] + bcol, 0.f));
            }
        }
    }
}

// ---------------- global add pool
__global__ __launch_bounds__(THREADS) void pool_kernel(
    const unsigned short* __restrict__ hbf,  // [N, 256] bf16
    const int*   __restrict__ batch,         // [N]
    float*       __restrict__ hg,            // [G, 256] f32
    int nnodes)
{
    constexpr int CH = 64;
    __shared__ int b_s[CH];
    const int t  = threadIdx.x;
    const int v0 = blockIdx.x * CH;
    int cnt = nnodes - v0;
    if (cnt > CH) cnt = CH;
    if (cnt <= 0) return;
    if (t < cnt) b_s[t] = batch[v0 + t];
    __syncthreads();

    int curb  = b_s[0];
    float acc = 0.f;
    for (int v = 0; v < cnt; v++) {
        int b = b_s[v];
        if (b != curb) {
            atomicAdd(&hg[(size_t)curb * 256 + t], acc);
            acc = 0.f; curb = b;
        }
        acc += bf2f(hbf[(size_t)(v0 + v) * 256 + t]);
    }
    atomicAdd(&hg[(size_t)curb * 256 + t], acc);
}

// ---------------- Bayesian weight materialization
__global__ void wprep_kernel(const float* __restrict__ mu,
                             const float* __restrict__ ls,
                             const float* __restrict__ eps,
                             float* __restrict__ w, int n)
{
    int i = blockIdx.x * THREADS + threadIdx.x;
    if (i < n) w[i] = mu[i] + expf(ls[i]) * eps[i];
}

// ---------------- head
__global__ __launch_bounds__(THREADS) void head_kernel(
    const float* __restrict__ hg,
    const float* __restrict__ w1,
    const float* __restrict__ h1_bmu, const float* __restrict__ h1_bls,
    const float* __restrict__ eps_b1,
    const float* __restrict__ h2_wmu, const float* __restrict__ h2_wls,
    const float* __restrict__ eps_w2,
    const float* __restrict__ h2_bmu, const float* __restrict__ h2_bls,
    const float* __restrict__ eps_b2,
    float* __restrict__ out)
{
    __shared__ float x_s[256];
    __shared__ float red[256];
    const int t = threadIdx.x;
    const int g = blockIdx.x;

    x_s[t] = hg[(size_t)g * 256 + t];
    __syncthreads();

    float acc = h1_bmu[t] + expf(h1_bls[t]) * eps_b1[t];
    for (int kk = 0; kk < 256; kk++) acc += x_s[kk] * w1[kk * 256 + t];
    float h1v = acc / (1.f + expf(-acc));

    float w2a = h2_wmu[t * 2 + 0] + expf(h2_wls[t * 2 + 0]) * eps_w2[t * 2 + 0];
    float w2b = h2_wmu[t * 2 + 1] + expf(h2_wls[t * 2 + 1]) * eps_w2[t * 2 + 1];

    red[t] = h1v * w2a;
    __syncthreads();
    for (int s = 128; s > 0; s >>= 1) {
        if (t < s) red[t] += red[t + s];
        __syncthreads();
    }
    if (t == 0) out[(size_t)g * 2 + 0] = red[0] + h2_bmu[0] + expf(h2_bls[0]) * eps_b2[0];
    __syncthreads();

    red[t] = h1v * w2b;
    __syncthreads();
    for (int s = 128; s > 0; s >>= 1) {
        if (t < s) red[t] += red[t + s];
        __syncthreads();
    }
    if (t == 0) out[(size_t)g * 2 + 1] = red[0] + h2_bmu[1] + expf(h2_bls[1]) * eps_b2[1];
}

// ---------------------------------------------------------------------------
extern "C" void kernel_launch(void* const* d_in, const int* in_sizes, int n_in,
                              void* d_out, int out_size, void* d_ws, size_t ws_size,
                              hipStream_t stream)
{
    const float* x         = (const float*)d_in[0];
    const float* edge_attr = (const float*)d_in[1];
    const int*   ei        = (const int*)d_in[2];
    const int*   batch     = (const int*)d_in[3];

    const float* We[3]  = { (const float*)d_in[4],  (const float*)d_in[11], (const float*)d_in[18] };
    const float* be[3]  = { (const float*)d_in[5],  (const float*)d_in[12], (const float*)d_in[19] };
    const float* W1[3]  = { (const float*)d_in[6],  (const float*)d_in[13], (const float*)d_in[20] };
    const float* b1[3]  = { (const float*)d_in[7],  (const float*)d_in[14], (const float*)d_in[21] };
    const float* W2[3]  = { (const float*)d_in[8],  (const float*)d_in[15], (const float*)d_in[22] };
    const float* b2[3]  = { (const float*)d_in[9],  (const float*)d_in[16], (const float*)d_in[23] };
    const float* epsl[3]= { (const float*)d_in[10], (const float*)d_in[17], (const float*)d_in[24] };

    const float* h1_wmu = (const float*)d_in[25];
    const float* h1_wls = (const float*)d_in[26];
    const float* h1_bmu = (const float*)d_in[27];
    const float* h1_bls = (const float*)d_in[28];
    const float* h2_wmu = (const float*)d_in[29];
    const float* h2_wls = (const float*)d_in[30];
    const float* h2_bmu = (const float*)d_in[31];
    const float* h2_bls = (const float*)d_in[32];
    const float* eps_w1 = (const float*)d_in[33];
    const float* eps_b1 = (const float*)d_in[34];
    const float* eps_w2 = (const float*)d_in[35];
    const float* eps_b2 = (const float*)d_in[36];

    const int N = in_sizes[0] / 128;
    const int E = in_sizes[1] / 16;
    const int G = out_size / 2;

    // ---- carve workspace (256B aligned chunks)
    uintptr_t p = (uintptr_t)d_ws;
    auto carve = [&](size_t bytes) -> void* {
        void* r = (void*)p;
        p = (p + bytes + 255) & ~(uintptr_t)255;
        return r;
    };
    float* hg      = (float*)carve((size_t)G * 256 * 4);
    float* w1buf   = (float*)carve(256 * 256 * 4);
    float* aggf    = (float*)carve((size_t)N * 256 * 4);
    int*   rowptr  = (int*)carve((size_t)(N + 1) * 4);
    int*   cursor  = (int*)carve((size_t)N * 4);
    int*   csr_src = (int*)carve((size_t)E * 4);
    int*   csr_dst = (int*)carve((size_t)E * 4);
    int*   csr_eid = (int*)carve((size_t)E * 4);
    unsigned short* ea16  = (unsigned short*)carve((size_t)E * 16 * 2);
    unsigned short* hbf   = (unsigned short*)carve((size_t)N * 256 * 2);
    unsigned short* tmpbf = (unsigned short*)carve((size_t)N * 256 * 2);
    unsigned short* xbf   = (unsigned short*)carve((size_t)N * 128 * 2);
    unsigned short* wep[3];
    wep[0] = (unsigned short*)carve(128 * 32 * 2);
    wep[1] = (unsigned short*)carve(256 * 32 * 2);
    wep[2] = (unsigned short*)carve(256 * 32 * 2);
    unsigned short* wt1[3], *wt2[3];
    wt1[0] = (unsigned short*)carve(256 * 128 * 2);
    for (int l = 0; l < 3; l++) {
        if (l) wt1[l] = (unsigned short*)carve(256 * 256 * 2);
        wt2[l] = (unsigned short*)carve(256 * 256 * 2);
    }

    const int eblocks     = (E + THREADS - 1) / THREADS;
    const int pool_blocks = (N + 63) / 64;
    const dim3 ggrid((N + 127) / 128, 2);

    float* out = (float*)d_out;

    // ---- build CSR once
    hipMemsetAsync(cursor, 0, (size_t)N * sizeof(int), stream);
    hist_kernel<<<eblocks, THREADS, 0, stream>>>(ei, cursor, E);
    scan_kernel<<<1, 1024, 0, stream>>>(cursor, rowptr, N);
    hipMemsetAsync(cursor, 0, (size_t)N * sizeof(int), stream);
    fill_kernel<<<eblocks, THREADS, 0, stream>>>(ei, rowptr, cursor, csr_src, csr_dst, csr_eid, E);
    easort_kernel<<<eblocks, THREADS, 0, stream>>>(edge_attr, csr_eid, ea16, E);
    xprep_kernel<<<(N * 32 + THREADS - 1) / THREADS, THREADS, 0, stream>>>(x, xbf, N * 32);

    // ---- weight prep
    wetrans_kernel<<<1, 128, 0, stream>>>(We[0], wep[0], 128);
    wetrans_kernel<<<1, 256, 0, stream>>>(We[1], wep[1], 256);
    wetrans_kernel<<<1, 256, 0, stream>>>(We[2], wep[2], 256);
    wtrans_kernel<<<dim3(4, 8), THREADS, 0, stream>>>(W1[0], wt1[0], 128);
    wtrans_kernel<<<dim3(8, 8), THREADS, 0, stream>>>(W2[0], wt2[0], 256);
    for (int l = 1; l < 3; l++) {
        wtrans_kernel<<<dim3(8, 8), THREADS, 0, stream>>>(W1[l], wt1[l], 256);
        wtrans_kernel<<<dim3(8, 8), THREADS, 0, stream>>>(W2[l], wt2[l], 256);
    }

    // ---- layer 0 (d = 128, h = xbf)
    hipMemsetAsync(aggf, 0, (size_t)N * 128 * sizeof(float), stream);
    edge_agg_kernel<128><<<(E + 63) / 64, THREADS, 0, stream>>>(
        xbf, ea16, csr_src, csr_dst, wep[0], be[0], aggf, E);
    mfma_mlp_kernel<128, 0><<<ggrid, THREADS, 0, stream>>>(
        xbf, aggf, wt1[0], b1[0], epsl[0], tmpbf, N);
    mfma_mlp_kernel<256, 1><<<ggrid, THREADS, 0, stream>>>(
        tmpbf, nullptr, wt2[0], b2[0], nullptr, hbf, N);

    // ---- layers 1, 2 (d = 256)
    for (int l = 1; l < 3; l++) {
        hipMemsetAsync(aggf, 0, (size_t)N * 256 * sizeof(float), stream);
        edge_agg_kernel<256><<<(E + 31) / 32, THREADS, 0, stream>>>(
            hbf, ea16, csr_src, csr_dst, wep[l], be[l], aggf, E);
        mfma_mlp_kernel<256, 0><<<ggrid, THREADS, 0, stream>>>(
            hbf, aggf, wt1[l], b1[l], epsl[l], tmpbf, N);
        mfma_mlp_kernel<256, 1><<<ggrid, THREADS, 0, stream>>>(
            tmpbf, nullptr, wt2[l], b2[l], nullptr, hbf, N);
    }

    // ---- global add pool -> hg
    hipMemsetAsync(hg, 0, (size_t)G * 256 * sizeof(float), stream);
    pool_kernel<<<pool_blocks, THREADS, 0, stream>>>(hbf, batch, hg, N);

    // ---- Bayesian head
    wprep_kernel<<<(256 * 256 + THREADS - 1) / THREADS, THREADS, 0, stream>>>(
        h1_wmu, h1_wls, eps_w1, w1buf, 256 * 256);
    head_kernel<<<G, THREADS, 0, stream>>>(
        hg, w1buf, h1_bmu, h1_bls, eps_b1,
        h2_wmu, h2_wls, eps_w2, h2_bmu, h2_bls, eps_b2, out);
}

// Round 8
// 787.743 us; speedup vs baseline: 4.6813x; 1.0499x over previous
//
#include <hip/hip_runtime.h>
#include <hip/hip_bf16.h>
#include <math.h>

// ---------------------------------------------------------------------------
// GINE x3 + global_add_pool + Bayesian head.
// Round 8: edge_agg phase-2 with explicit 16-load gather burst (ILP fix,
// run-length logic moved after the loads); shfl-based CSR scan (3 barriers
// per chunk instead of 21). Structure otherwise identical to R7.
// ---------------------------------------------------------------------------

#define THREADS 256

typedef __attribute__((ext_vector_type(8))) short bf16x8;
typedef __attribute__((ext_vector_type(4))) float f32x4;

__device__ __forceinline__ unsigned short f2bf(float x) {
    __hip_bfloat16 h = __float2bfloat16(x);
    return __builtin_bit_cast(unsigned short, h);
}
__device__ __forceinline__ float bflo(unsigned u) {
    return __builtin_bit_cast(float, u << 16);
}
__device__ __forceinline__ float bfhi(unsigned u) {
    return __builtin_bit_cast(float, u & 0xffff0000u);
}
__device__ __forceinline__ float bf2f(unsigned short u) {
    return __builtin_bit_cast(float, (unsigned)u << 16);
}
__device__ __forceinline__ unsigned pk(float a, float b) {
    return (unsigned)f2bf(a) | ((unsigned)f2bf(b) << 16);
}

// ---------------- CSR build: histogram of dst
__global__ __launch_bounds__(THREADS) void hist_kernel(
    const int* __restrict__ ei, int* __restrict__ deg, int E)
{
    int e = blockIdx.x * THREADS + threadIdx.x;
    if (e < E) atomicAdd(&deg[ei[E + e]], 1);
}

// ---------------- CSR build: wave-shuffle exclusive scan -> rowptr[0..n]
__global__ __launch_bounds__(1024) void scan_kernel(
    const int* __restrict__ deg, int* __restrict__ rowptr, int n)
{
    __shared__ int wsum[16];
    __shared__ int carry_s;
    const int t    = threadIdx.x;
    const int lane = t & 63, wv = t >> 6;
    if (t == 0) carry_s = 0;
    __syncthreads();
    for (int base = 0; base < n; base += 1024) {
        int i = base + t;
        int incl = (i < n) ? deg[i] : 0;
#pragma unroll
        for (int off = 1; off < 64; off <<= 1) {
            int u = __shfl_up(incl, off, 64);
            if (lane >= off) incl += u;
        }
        if (lane == 63) wsum[wv] = incl;
        __syncthreads();
        if (wv == 0) {
            int s = (lane < 16) ? wsum[lane] : 0;
#pragma unroll
            for (int off = 1; off < 16; off <<= 1) {
                int u = __shfl_up(s, off, 64);
                if (lane >= off) s += u;
            }
            if (lane < 16) wsum[lane] = s;   // inclusive wave sums
        }
        __syncthreads();
        int waveoff = (wv == 0) ? 0 : wsum[wv - 1];
        int carry   = carry_s;
        if (i < n) rowptr[i + 1] = carry + waveoff + incl;
        __syncthreads();
        if (t == 1023) carry_s = carry + wsum[15];
        __syncthreads();
    }
    if (t == 0) rowptr[0] = 0;
}

// ---------------- CSR build: scatter edge ids into slots (also csr_dst)
__global__ __launch_bounds__(THREADS) void fill_kernel(
    const int* __restrict__ ei, const int* __restrict__ rowptr,
    int* __restrict__ cursor, int* __restrict__ csr_src,
    int* __restrict__ csr_dst, int* __restrict__ csr_eid, int E)
{
    int e = blockIdx.x * THREADS + threadIdx.x;
    if (e >= E) return;
    int s = ei[e], d = ei[E + e];
    int pos  = atomicAdd(&cursor[d], 1);
    int slot = rowptr[d] + pos;
    csr_src[slot] = s;
    csr_dst[slot] = d;
    csr_eid[slot] = e;
}

// ---------------- edge_attr -> bf16 [E][16] in CSR slot order
__global__ __launch_bounds__(THREADS) void easort_kernel(
    const float* __restrict__ edge_attr, const int* __restrict__ csr_eid,
    unsigned short* __restrict__ ea16, int E)
{
    int s = blockIdx.x * THREADS + threadIdx.x;
    if (s >= E) return;
    int eid = csr_eid[s];
    const float4* a = (const float4*)(edge_attr + (size_t)eid * 16);
    float4 a0 = a[0], a1 = a[1], a2 = a[2], a3 = a[3];
    uint4* d = (uint4*)(ea16 + (size_t)s * 16);
    d[0] = make_uint4(pk(a0.x, a0.y), pk(a0.z, a0.w), pk(a1.x, a1.y), pk(a1.z, a1.w));
    d[1] = make_uint4(pk(a2.x, a2.y), pk(a2.z, a2.w), pk(a3.x, a3.y), pk(a3.z, a3.w));
}

// ---------------- x -> bf16 copy
__global__ __launch_bounds__(THREADS) void xprep_kernel(
    const float* __restrict__ x, unsigned short* __restrict__ xbf, int n4)
{
    int i = blockIdx.x * THREADS + threadIdx.x;
    if (i >= n4) return;
    float4 v = ((const float4*)x)[i];
    uint2 p;
    p.x = pk(v.x, v.y);
    p.y = pk(v.z, v.w);
    ((uint2*)xbf)[i] = p;
}

// ---------------- We[16][D] f32 -> Wtp[D][32] bf16 (k 16..31 zero)
__global__ __launch_bounds__(THREADS) void wetrans_kernel(
    const float* __restrict__ We, unsigned short* __restrict__ Wtp, int D)
{
    int f = blockIdx.x * THREADS + threadIdx.x;
    if (f >= D) return;
#pragma unroll
    for (int k = 0; k < 16; k++) Wtp[f * 32 + k] = f2bf(We[k * D + f]);
#pragma unroll
    for (int k = 16; k < 32; k++) Wtp[f * 32 + k] = 0;
}

// ---------------- fused MFMA aggregation:
// phase1: msg[f][e] = ea[e][:16] @ We[:,f] + be[f]  (MFMA, bias in C-init)
// phase2: agg[dst][f] += relu(h[src][f] + msg)
//         2 feats/thread, 16-edge consecutive window, 16-load gather burst,
//         run-length flush with coalesced f32 atomics
template<int D>
__global__ __launch_bounds__(THREADS) void edge_agg_kernel(
    const unsigned short* __restrict__ hbf,   // [N][D] bf16
    const unsigned short* __restrict__ ea16,  // [E][16] bf16, CSR order
    const int* __restrict__ csr_src,          // [E]
    const int* __restrict__ csr_dst,          // [E] (non-decreasing)
    const unsigned short* __restrict__ Wtp,   // [D][32] bf16, k>=16 zero
    const float* __restrict__ be,             // [D]
    float* __restrict__ agg,                  // [N][D] f32, pre-zeroed
    int E)
{
    constexpr int EPB = (D == 128) ? 64 : 32;    // edges per block
    constexpr int LDF = D + 8;                   // padded LDS stride (shorts)
    __shared__ unsigned short msg[EPB * LDF];
    __shared__ int src_s[EPB], dst_s[EPB];

    const int t    = threadIdx.x;
    const int e0   = blockIdx.x * EPB;
    const int lane = t & 63, wid = t >> 6;
    const int l15  = lane & 15, lgr = lane >> 4;

    // stage src/dst for phase 2 (tail zero-padded: safe fake edges)
    for (int i = t; i < EPB; i += THREADS) {
        int e = e0 + i;
        src_s[i] = (e < E) ? csr_src[e] : 0;
        dst_s[i] = (e < E) ? csr_dst[e] : 0;
    }

    // ---- phase 1: MFMA projection, C[feature][edge], bias in C-init
    const int fb = (D == 128) ? (wid & 1) * 64 : wid * 64;   // feature base
    const int eb = (D == 128) ? (wid >> 1) * 32 : 0;         // edge base

    bf16x8 af[4];
#pragma unroll
    for (int mf = 0; mf < 4; mf++)
        af[mf] = *(const bf16x8*)(Wtp + (size_t)(fb + mf * 16 + l15) * 32 + lgr * 8);

    f32x4 acc[4][2];
#pragma unroll
    for (int mf = 0; mf < 4; mf++) {
        int fpos = fb + mf * 16 + lgr * 4;
        float4 bv4 = *(const float4*)(be + fpos);
        f32x4 binit = (f32x4){bv4.x, bv4.y, bv4.z, bv4.w};
        acc[mf][0] = binit;
        acc[mf][1] = binit;
    }

#pragma unroll
    for (int nf = 0; nf < 2; nf++) {
        int er = e0 + eb + nf * 16 + l15;
        bf16x8 bv = (bf16x8){0, 0, 0, 0, 0, 0, 0, 0};
        if (lgr < 2 && er < E)
            bv = *(const bf16x8*)(ea16 + (size_t)er * 16 + lgr * 8);
#pragma unroll
        for (int mf = 0; mf < 4; mf++)
            acc[mf][nf] = __builtin_amdgcn_mfma_f32_16x16x32_bf16(
                af[mf], bv, acc[mf][nf], 0, 0, 0);
    }

    // write msg tile to LDS (bf16)
#pragma unroll
    for (int nf = 0; nf < 2; nf++) {
        int edge = eb + nf * 16 + l15;
#pragma unroll
        for (int mf = 0; mf < 4; mf++) {
            int fpos = fb + mf * 16 + lgr * 4;
            f32x4 v = acc[mf][nf];
            uint2 p;
            p.x = pk(v[0], v[1]);
            p.y = pk(v[2], v[3]);
            *(uint2*)(&msg[edge * LDF + fpos]) = p;
        }
    }
    __syncthreads();

    // ---- phase 2: gather burst then run-length accumulate
    constexpr int LPF = D / 2;             // thread-pairs covering features
    const int f2   = (t & (LPF - 1)) * 2;  // feature pair
    const int win  = t / LPF;              // window index
    const int base = win * 16;

    // burst: 16 independent gathers in flight
    unsigned hv[16];
#pragma unroll
    for (int i = 0; i < 16; i++) {
        int src = src_s[base + i];
        hv[i] = *(const unsigned*)(hbf + (size_t)src * D + f2);
    }

    float a0 = 0.f, a1 = 0.f;
    int cur = dst_s[base];
#pragma unroll
    for (int i = 0; i < 16; ++i) {
        int el = base + i;
        int d  = dst_s[el];
        unsigned pv = *(const unsigned*)(&msg[el * LDF + f2]);
        float m0 = fmaxf(bflo(hv[i]) + bflo(pv), 0.f);
        float m1 = fmaxf(bfhi(hv[i]) + bfhi(pv), 0.f);
        if (d != cur) {
            atomicAdd(&agg[(size_t)cur * D + f2],     a0);
            atomicAdd(&agg[(size_t)cur * D + f2 + 1], a1);
            a0 = 0.f; a1 = 0.f;
            cur = d;
        }
        bool ok = (e0 + el < E);
        a0 += ok ? m0 : 0.f;
        a1 += ok ? m1 : 0.f;
    }
    atomicAdd(&agg[(size_t)cur * D + f2],     a0);
    atomicAdd(&agg[(size_t)cur * D + f2 + 1], a1);
}

// ---------------- W transpose + bf16 convert: W[K,256] f32 -> Wt[256,K] bf16
__global__ __launch_bounds__(THREADS) void wtrans_kernel(
    const float* __restrict__ W, unsigned short* __restrict__ Wt, int K)
{
    __shared__ float tile[32][33];
    const int kb = blockIdx.x * 32, nb = blockIdx.y * 32;
    const int tx = threadIdx.x & 31, ty = threadIdx.x >> 5;
#pragma unroll
    for (int i = ty; i < 32; i += 8)
        tile[i][tx] = W[(size_t)(kb + i) * 256 + nb + tx];
    __syncthreads();
#pragma unroll
    for (int i = ty; i < 32; i += 8)
        Wt[(size_t)(nb + i) * K + kb + tx] = f2bf(tile[tx][i]);
}

// ---------------- MFMA node-MLP GEMM (bf16 h in, bf16 out):
// MODE 0: A = (1+eps)*hin + agg(f32)    MODE 1: A = hin
template<int K, int MODE>
__global__ __launch_bounds__(THREADS) void mfma_mlp_kernel(
    const unsigned short* __restrict__ hin,   // [nrows, K] bf16
    const float* __restrict__ agg,            // [nrows, K] f32 (MODE 0)
    const unsigned short* __restrict__ Wt,    // [256, K] bf16
    const float* __restrict__ bias,           // [256]
    const float* __restrict__ epsp,           // [1] (MODE 0)
    unsigned short* __restrict__ out,         // [nrows, 256] bf16
    int nrows)
{
    constexpr int BM = 128, BK = 64;
    constexpr int LDR = BK + 8;
    __shared__ short As[BM * LDR];
    __shared__ short Bs[128 * LDR];

    const int t    = threadIdx.x;
    const int lane = t & 63;
    const int wid  = t >> 6;
    const int wm   = wid >> 1, wn = wid & 1;
    const int l15  = lane & 15, lgr = lane >> 4;

    const int r0 = blockIdx.x * BM;
    const int n0 = blockIdx.y * 128;

    float scale = 1.0f;
    if (MODE == 0) scale = 1.0f + epsp[0];

    f32x4 acc[4][4];
#pragma unroll
    for (int a = 0; a < 4; a++)
#pragma unroll
        for (int b = 0; b < 4; b++) acc[a][b] = (f32x4){0.f, 0.f, 0.f, 0.f};

    for (int k0 = 0; k0 < K; k0 += BK) {
#pragma unroll
        for (int c = 0; c < 4; c++) {
            int idx = t + c * THREADS;
            int r   = idx >> 3;
            int kq  = idx & 7;
            int row = r0 + r;
            uint4 o = make_uint4(0, 0, 0, 0);
            if (row < nrows) {
                size_t g = (size_t)row * K + k0 + kq * 8;
                uint4 hv = *(const uint4*)(hin + g);
                if (MODE == 0) {
                    float4 a0 = *(const float4*)(agg + g);
                    float4 a1 = *(const float4*)(agg + g + 4);
                    o.x = pk(scale * bflo(hv.x) + a0.x, scale * bfhi(hv.x) + a0.y);
                    o.y = pk(scale * bflo(hv.y) + a0.z, scale * bfhi(hv.y) + a0.w);
                    o.z = pk(scale * bflo(hv.z) + a1.x, scale * bfhi(hv.z) + a1.y);
                    o.w = pk(scale * bflo(hv.w) + a1.z, scale * bfhi(hv.w) + a1.w);
                } else {
                    o = hv;
                }
            }
            *(uint4*)(&As[r * LDR + kq * 8]) = o;
        }
#pragma unroll
        for (int c = 0; c < 4; c++) {
            int idx = t + c * THREADS;
            int n   = idx >> 3;
            int kq  = idx & 7;
            uint4 w = *(const uint4*)(Wt + (size_t)(n0 + n) * K + k0 + kq * 8);
            *(uint4*)(&Bs[n * LDR + kq * 8]) = w;
        }
        __syncthreads();

#pragma unroll
        for (int ks = 0; ks < 2; ks++) {
            bf16x8 af[4], bfr[4];
#pragma unroll
            for (int mf = 0; mf < 4; mf++)
                af[mf] = *(const bf16x8*)(&As[(wm * 64 + mf * 16 + l15) * LDR + ks * 32 + lgr * 8]);
#pragma unroll
            for (int nf = 0; nf < 4; nf++)
                bfr[nf] = *(const bf16x8*)(&Bs[(wn * 64 + nf * 16 + l15) * LDR + ks * 32 + lgr * 8]);
#pragma unroll
            for (int mf = 0; mf < 4; mf++)
#pragma unroll
                for (int nf = 0; nf < 4; nf++)
                    acc[mf][nf] = __builtin_amdgcn_mfma_f32_16x16x32_bf16(
                        af[mf], bfr[nf], acc[mf][nf], 0, 0, 0);
        }
        __syncthreads();
    }

#pragma unroll
    for (int nf = 0; nf < 4; nf++) {
        int col = n0 + wn * 64 + nf * 16 + l15;
        float bcol = bias[col];
#pragma unroll
        for (int mf = 0; mf < 4; mf++) {
            f32x4 v = acc[mf][nf];
#pragma unroll
            for (int r = 0; r < 4; r++) {
                int row = r0 + wm * 64 + mf * 16 + lgr * 4 + r;
                if (row < nrows)
                    out[(size_t)row * 256 + col] = f2bf(fmaxf(v[r] + bcol, 0.f));
            }
        }
    }
}

// ---------------- global add pool
__global__ __launch_bounds__(THREADS) void pool_kernel(
    const unsigned short* __restrict__ hbf,  // [N, 256] bf16
    const int*   __restrict__ batch,         // [N]
    float*       __restrict__ hg,            // [G, 256] f32
    int nnodes)
{
    constexpr int CH = 64;
    __shared__ int b_s[CH];
    const int t  = threadIdx.x;
    const int v0 = blockIdx.x * CH;
    int cnt = nnodes - v0;
    if (cnt > CH) cnt = CH;
    if (cnt <= 0) return;
    if (t < cnt) b_s[t] = batch[v0 + t];
    __syncthreads();

    int curb  = b_s[0];
    float acc = 0.f;
    for (int v = 0; v < cnt; v++) {
        int b = b_s[v];
        if (b != curb) {
            atomicAdd(&hg[(size_t)curb * 256 + t], acc);
            acc = 0.f; curb = b;
        }
        acc += bf2f(hbf[(size_t)(v0 + v) * 256 + t]);
    }
    atomicAdd(&hg[(size_t)curb * 256 + t], acc);
}

// ---------------- Bayesian weight materialization
__global__ void wprep_kernel(const float* __restrict__ mu,
                             const float* __restrict__ ls,
                             const float* __restrict__ eps,
                             float* __restrict__ w, int n)
{
    int i = blockIdx.x * THREADS + threadIdx.x;
    if (i < n) w[i] = mu[i] + expf(ls[i]) * eps[i];
}

// ---------------- head
__global__ __launch_bounds__(THREADS) void head_kernel(
    const float* __restrict__ hg,
    const float* __restrict__ w1,
    const float* __restrict__ h1_bmu, const float* __restrict__ h1_bls,
    const float* __restrict__ eps_b1,
    const float* __restrict__ h2_wmu, const float* __restrict__ h2_wls,
    const float* __restrict__ eps_w2,
    const float* __restrict__ h2_bmu, const float* __restrict__ h2_bls,
    const float* __restrict__ eps_b2,
    float* __restrict__ out)
{
    __shared__ float x_s[256];
    __shared__ float red[256];
    const int t = threadIdx.x;
    const int g = blockIdx.x;

    x_s[t] = hg[(size_t)g * 256 + t];
    __syncthreads();

    float acc = h1_bmu[t] + expf(h1_bls[t]) * eps_b1[t];
    for (int kk = 0; kk < 256; kk++) acc += x_s[kk] * w1[kk * 256 + t];
    float h1v = acc / (1.f + expf(-acc));

    float w2a = h2_wmu[t * 2 + 0] + expf(h2_wls[t * 2 + 0]) * eps_w2[t * 2 + 0];
    float w2b = h2_wmu[t * 2 + 1] + expf(h2_wls[t * 2 + 1]) * eps_w2[t * 2 + 1];

    red[t] = h1v * w2a;
    __syncthreads();
    for (int s = 128; s > 0; s >>= 1) {
        if (t < s) red[t] += red[t + s];
        __syncthreads();
    }
    if (t == 0) out[(size_t)g * 2 + 0] = red[0] + h2_bmu[0] + expf(h2_bls[0]) * eps_b2[0];
    __syncthreads();

    red[t] = h1v * w2b;
    __syncthreads();
    for (int s = 128; s > 0; s >>= 1) {
        if (t < s) red[t] += red[t + s];
        __syncthreads();
    }
    if (t == 0) out[(size_t)g * 2 + 1] = red[0] + h2_bmu[1] + expf(h2_bls[1]) * eps_b2[1];
}

// ---------------------------------------------------------------------------
extern "C" void kernel_launch(void* const* d_in, const int* in_sizes, int n_in,
                              void* d_out, int out_size, void* d_ws, size_t ws_size,
                              hipStream_t stream)
{
    const float* x         = (const float*)d_in[0];
    const float* edge_attr = (const float*)d_in[1];
    const int*   ei        = (const int*)d_in[2];
    const int*   batch     = (const int*)d_in[3];

    const float* We[3]  = { (const float*)d_in[4],  (const float*)d_in[11], (const float*)d_in[18] };
    const float* be[3]  = { (const float*)d_in[5],  (const float*)d_in[12], (const float*)d_in[19] };
    const float* W1[3]  = { (const float*)d_in[6],  (const float*)d_in[13], (const float*)d_in[20] };
    const float* b1[3]  = { (const float*)d_in[7],  (const float*)d_in[14], (const float*)d_in[21] };
    const float* W2[3]  = { (const float*)d_in[8],  (const float*)d_in[15], (const float*)d_in[22] };
    const float* b2[3]  = { (const float*)d_in[9],  (const float*)d_in[16], (const float*)d_in[23] };
    const float* epsl[3]= { (const float*)d_in[10], (const float*)d_in[17], (const float*)d_in[24] };

    const float* h1_wmu = (const float*)d_in[25];
    const float* h1_wls = (const float*)d_in[26];
    const float* h1_bmu = (const float*)d_in[27];
    const float* h1_bls = (const float*)d_in[28];
    const float* h2_wmu = (const float*)d_in[29];
    const float* h2_wls = (const float*)d_in[30];
    const float* h2_bmu = (const float*)d_in[31];
    const float* h2_bls = (const float*)d_in[32];
    const float* eps_w1 = (const float*)d_in[33];
    const float* eps_b1 = (const float*)d_in[34];
    const float* eps_w2 = (const float*)d_in[35];
    const float* eps_b2 = (const float*)d_in[36];

    const int N = in_sizes[0] / 128;
    const int E = in_sizes[1] / 16;
    const int G = out_size / 2;

    // ---- carve workspace (256B aligned chunks)
    uintptr_t p = (uintptr_t)d_ws;
    auto carve = [&](size_t bytes) -> void* {
        void* r = (void*)p;
        p = (p + bytes + 255) & ~(uintptr_t)255;
        return r;
    };
    float* hg      = (float*)carve((size_t)G * 256 * 4);
    float* w1buf   = (float*)carve(256 * 256 * 4);
    float* aggf    = (float*)carve((size_t)N * 256 * 4);
    int*   rowptr  = (int*)carve((size_t)(N + 1) * 4);
    int*   cursor  = (int*)carve((size_t)N * 4);
    int*   csr_src = (int*)carve((size_t)E * 4);
    int*   csr_dst = (int*)carve((size_t)E * 4);
    int*   csr_eid = (int*)carve((size_t)E * 4);
    unsigned short* ea16  = (unsigned short*)carve((size_t)E * 16 * 2);
    unsigned short* hbf   = (unsigned short*)carve((size_t)N * 256 * 2);
    unsigned short* tmpbf = (unsigned short*)carve((size_t)N * 256 * 2);
    unsigned short* xbf   = (unsigned short*)carve((size_t)N * 128 * 2);
    unsigned short* wep[3];
    wep[0] = (unsigned short*)carve(128 * 32 * 2);
    wep[1] = (unsigned short*)carve(256 * 32 * 2);
    wep[2] = (unsigned short*)carve(256 * 32 * 2);
    unsigned short* wt1[3], *wt2[3];
    wt1[0] = (unsigned short*)carve(256 * 128 * 2);
    for (int l = 0; l < 3; l++) {
        if (l) wt1[l] = (unsigned short*)carve(256 * 256 * 2);
        wt2[l] = (unsigned short*)carve(256 * 256 * 2);
    }

    const int eblocks     = (E + THREADS - 1) / THREADS;
    const int pool_blocks = (N + 63) / 64;
    const dim3 ggrid((N + 127) / 128, 2);

    float* out = (float*)d_out;

    // ---- build CSR once
    hipMemsetAsync(cursor, 0, (size_t)N * sizeof(int), stream);
    hist_kernel<<<eblocks, THREADS, 0, stream>>>(ei, cursor, E);
    scan_kernel<<<1, 1024, 0, stream>>>(cursor, rowptr, N);
    hipMemsetAsync(cursor, 0, (size_t)N * sizeof(int), stream);
    fill_kernel<<<eblocks, THREADS, 0, stream>>>(ei, rowptr, cursor, csr_src, csr_dst, csr_eid, E);
    easort_kernel<<<eblocks, THREADS, 0, stream>>>(edge_attr, csr_eid, ea16, E);
    xprep_kernel<<<(N * 32 + THREADS - 1) / THREADS, THREADS, 0, stream>>>(x, xbf, N * 32);

    // ---- weight prep
    wetrans_kernel<<<1, 128, 0, stream>>>(We[0], wep[0], 128);
    wetrans_kernel<<<1, 256, 0, stream>>>(We[1], wep[1], 256);
    wetrans_kernel<<<1, 256, 0, stream>>>(We[2], wep[2], 256);
    wtrans_kernel<<<dim3(4, 8), THREADS, 0, stream>>>(W1[0], wt1[0], 128);
    wtrans_kernel<<<dim3(8, 8), THREADS, 0, stream>>>(W2[0], wt2[0], 256);
    for (int l = 1; l < 3; l++) {
        wtrans_kernel<<<dim3(8, 8), THREADS, 0, stream>>>(W1[l], wt1[l], 256);
        wtrans_kernel<<<dim3(8, 8), THREADS, 0, stream>>>(W2[l], wt2[l], 256);
    }

    // ---- layer 0 (d = 128, h = xbf)
    hipMemsetAsync(aggf, 0, (size_t)N * 128 * sizeof(float), stream);
    edge_agg_kernel<128><<<(E + 63) / 64, THREADS, 0, stream>>>(
        xbf, ea16, csr_src, csr_dst, wep[0], be[0], aggf, E);
    mfma_mlp_kernel<128, 0><<<ggrid, THREADS, 0, stream>>>(
        xbf, aggf, wt1[0], b1[0], epsl[0], tmpbf, N);
    mfma_mlp_kernel<256, 1><<<ggrid, THREADS, 0, stream>>>(
        tmpbf, nullptr, wt2[0], b2[0], nullptr, hbf, N);

    // ---- layers 1, 2 (d = 256)
    for (int l = 1; l < 3; l++) {
        hipMemsetAsync(aggf, 0, (size_t)N * 256 * sizeof(float), stream);
        edge_agg_kernel<256><<<(E + 31) / 32, THREADS, 0, stream>>>(
            hbf, ea16, csr_src, csr_dst, wep[l], be[l], aggf, E);
        mfma_mlp_kernel<256, 0><<<ggrid, THREADS, 0, stream>>>(
            hbf, aggf, wt1[l], b1[l], epsl[l], tmpbf, N);
        mfma_mlp_kernel<256, 1><<<ggrid, THREADS, 0, stream>>>(
            tmpbf, nullptr, wt2[l], b2[l], nullptr, hbf, N);
    }

    // ---- global add pool -> hg
    hipMemsetAsync(hg, 0, (size_t)G * 256 * sizeof(float), stream);
    pool_kernel<<<pool_blocks, THREADS, 0, stream>>>(hbf, batch, hg, N);

    // ---- Bayesian head
    wprep_kernel<<<(256 * 256 + THREADS - 1) / THREADS, THREADS, 0, stream>>>(
        h1_wmu, h1_wls, eps_w1, w1buf, 256 * 256);
    head_kernel<<<G, THREADS, 0, stream>>>(
        hg, w1buf, h1_bmu, h1_bls, eps_b1,
        h2_wmu, h2_wls, eps_w2, h2_bmu, h2_bls, eps_b2, out);
}

// Round 9
// 591.237 us; speedup vs baseline: 6.2372x; 1.3324x over previous
//
#include <hip/hip_runtime.h>
#include <hip/hip_bf16.h>
#include <math.h>

// ---------------------------------------------------------------------------
// GINE x3 + global_add_pool + Bayesian head.
// Round 9: agg in bf16 via global_atomic_pk_add_bf16 (packed, halves atomic
// count) + full-segment plain-store fast path (no RMW for ~44% of nodes).
// dst staged for [e0-1, e0+EPB] to detect run start/end; fake edges dst=-1.
// ---------------------------------------------------------------------------

#define THREADS 256

typedef __attribute__((ext_vector_type(8))) short bf16x8;
typedef __attribute__((ext_vector_type(4))) float f32x4;

__device__ __forceinline__ unsigned short f2bf(float x) {
    __hip_bfloat16 h = __float2bfloat16(x);
    return __builtin_bit_cast(unsigned short, h);
}
__device__ __forceinline__ float bflo(unsigned u) {
    return __builtin_bit_cast(float, u << 16);
}
__device__ __forceinline__ float bfhi(unsigned u) {
    return __builtin_bit_cast(float, u & 0xffff0000u);
}
__device__ __forceinline__ float bf2f(unsigned short u) {
    return __builtin_bit_cast(float, (unsigned)u << 16);
}
__device__ __forceinline__ unsigned pk(float a, float b) {
    return (unsigned)f2bf(a) | ((unsigned)f2bf(b) << 16);
}

// ---------------- CSR build: histogram of dst
__global__ __launch_bounds__(THREADS) void hist_kernel(
    const int* __restrict__ ei, int* __restrict__ deg, int E)
{
    int e = blockIdx.x * THREADS + threadIdx.x;
    if (e < E) atomicAdd(&deg[ei[E + e]], 1);
}

// ---------------- CSR build: wave-shuffle exclusive scan -> rowptr[0..n]
__global__ __launch_bounds__(1024) void scan_kernel(
    const int* __restrict__ deg, int* __restrict__ rowptr, int n)
{
    __shared__ int wsum[16];
    __shared__ int carry_s;
    const int t    = threadIdx.x;
    const int lane = t & 63, wv = t >> 6;
    if (t == 0) carry_s = 0;
    __syncthreads();
    for (int base = 0; base < n; base += 1024) {
        int i = base + t;
        int incl = (i < n) ? deg[i] : 0;
#pragma unroll
        for (int off = 1; off < 64; off <<= 1) {
            int u = __shfl_up(incl, off, 64);
            if (lane >= off) incl += u;
        }
        if (lane == 63) wsum[wv] = incl;
        __syncthreads();
        if (wv == 0) {
            int s = (lane < 16) ? wsum[lane] : 0;
#pragma unroll
            for (int off = 1; off < 16; off <<= 1) {
                int u = __shfl_up(s, off, 64);
                if (lane >= off) s += u;
            }
            if (lane < 16) wsum[lane] = s;   // inclusive wave sums
        }
        __syncthreads();
        int waveoff = (wv == 0) ? 0 : wsum[wv - 1];
        int carry   = carry_s;
        if (i < n) rowptr[i + 1] = carry + waveoff + incl;
        __syncthreads();
        if (t == 1023) carry_s = carry + wsum[15];
        __syncthreads();
    }
    if (t == 0) rowptr[0] = 0;
}

// ---------------- CSR build: scatter edge ids into slots (also csr_dst)
__global__ __launch_bounds__(THREADS) void fill_kernel(
    const int* __restrict__ ei, const int* __restrict__ rowptr,
    int* __restrict__ cursor, int* __restrict__ csr_src,
    int* __restrict__ csr_dst, int* __restrict__ csr_eid, int E)
{
    int e = blockIdx.x * THREADS + threadIdx.x;
    if (e >= E) return;
    int s = ei[e], d = ei[E + e];
    int pos  = atomicAdd(&cursor[d], 1);
    int slot = rowptr[d] + pos;
    csr_src[slot] = s;
    csr_dst[slot] = d;
    csr_eid[slot] = e;
}

// ---------------- edge_attr -> bf16 [E][16] in CSR slot order
__global__ __launch_bounds__(THREADS) void easort_kernel(
    const float* __restrict__ edge_attr, const int* __restrict__ csr_eid,
    unsigned short* __restrict__ ea16, int E)
{
    int s = blockIdx.x * THREADS + threadIdx.x;
    if (s >= E) return;
    int eid = csr_eid[s];
    const float4* a = (const float4*)(edge_attr + (size_t)eid * 16);
    float4 a0 = a[0], a1 = a[1], a2 = a[2], a3 = a[3];
    uint4* d = (uint4*)(ea16 + (size_t)s * 16);
    d[0] = make_uint4(pk(a0.x, a0.y), pk(a0.z, a0.w), pk(a1.x, a1.y), pk(a1.z, a1.w));
    d[1] = make_uint4(pk(a2.x, a2.y), pk(a2.z, a2.w), pk(a3.x, a3.y), pk(a3.z, a3.w));
}

// ---------------- x -> bf16 copy
__global__ __launch_bounds__(THREADS) void xprep_kernel(
    const float* __restrict__ x, unsigned short* __restrict__ xbf, int n4)
{
    int i = blockIdx.x * THREADS + threadIdx.x;
    if (i >= n4) return;
    float4 v = ((const float4*)x)[i];
    uint2 p;
    p.x = pk(v.x, v.y);
    p.y = pk(v.z, v.w);
    ((uint2*)xbf)[i] = p;
}

// ---------------- We[16][D] f32 -> Wtp[D][32] bf16 (k 16..31 zero)
__global__ __launch_bounds__(THREADS) void wetrans_kernel(
    const float* __restrict__ We, unsigned short* __restrict__ Wtp, int D)
{
    int f = blockIdx.x * THREADS + threadIdx.x;
    if (f >= D) return;
#pragma unroll
    for (int k = 0; k < 16; k++) Wtp[f * 32 + k] = f2bf(We[k * D + f]);
#pragma unroll
    for (int k = 16; k < 32; k++) Wtp[f * 32 + k] = 0;
}

// ---------------- fused MFMA aggregation:
// phase1: msg[f][e] = ea[e][:16] @ We[:,f] + be[f]  (MFMA, bias in C-init)
// phase2: agg[dst][f] += relu(h[src][f] + msg)  -> bf16 agg, packed atomics;
//         full-in-window segments use a plain store (no RMW).
template<int D>
__global__ __launch_bounds__(THREADS) void edge_agg_kernel(
    const unsigned short* __restrict__ hbf,   // [N][D] bf16
    const unsigned short* __restrict__ ea16,  // [E][16] bf16, CSR order
    const int* __restrict__ csr_src,          // [E]
    const int* __restrict__ csr_dst,          // [E] (non-decreasing)
    const unsigned short* __restrict__ Wtp,   // [D][32] bf16, k>=16 zero
    const float* __restrict__ be,             // [D]
    unsigned short* __restrict__ agg,         // [N][D] bf16, pre-zeroed
    int E)
{
    constexpr int EPB = (D == 128) ? 64 : 32;    // edges per block
    constexpr int LDF = D + 8;                   // padded LDS stride (shorts)
    __shared__ unsigned short msg[EPB * LDF];
    __shared__ int src_s[EPB];
    __shared__ int dst_x[EPB + 2];               // dst of edges e0-1 .. e0+EPB

    const int t    = threadIdx.x;
    const int e0   = blockIdx.x * EPB;
    const int lane = t & 63, wid = t >> 6;
    const int l15  = lane & 15, lgr = lane >> 4;

    // stage src (tail: safe fake src 0) and extended dst (sentinels)
    for (int i = t; i < EPB; i += THREADS) {
        int e = e0 + i;
        src_s[i] = (e < E) ? csr_src[e] : 0;
    }
    for (int i = t; i < EPB + 2; i += THREADS) {
        int e = e0 + i - 1;
        dst_x[i] = (e < 0) ? -2 : ((e < E) ? csr_dst[e] : -1);
    }

    // ---- phase 1: MFMA projection, C[feature][edge], bias in C-init
    const int fb = (D == 128) ? (wid & 1) * 64 : wid * 64;   // feature base
    const int eb = (D == 128) ? (wid >> 1) * 32 : 0;         // edge base

    bf16x8 af[4];
#pragma unroll
    for (int mf = 0; mf < 4; mf++)
        af[mf] = *(const bf16x8*)(Wtp + (size_t)(fb + mf * 16 + l15) * 32 + lgr * 8);

    f32x4 acc[4][2];
#pragma unroll
    for (int mf = 0; mf < 4; mf++) {
        int fpos = fb + mf * 16 + lgr * 4;
        float4 bv4 = *(const float4*)(be + fpos);
        f32x4 binit = (f32x4){bv4.x, bv4.y, bv4.z, bv4.w};
        acc[mf][0] = binit;
        acc[mf][1] = binit;
    }

#pragma unroll
    for (int nf = 0; nf < 2; nf++) {
        int er = e0 + eb + nf * 16 + l15;
        bf16x8 bv = (bf16x8){0, 0, 0, 0, 0, 0, 0, 0};
        if (lgr < 2 && er < E)
            bv = *(const bf16x8*)(ea16 + (size_t)er * 16 + lgr * 8);
#pragma unroll
        for (int mf = 0; mf < 4; mf++)
            acc[mf][nf] = __builtin_amdgcn_mfma_f32_16x16x32_bf16(
                af[mf], bv, acc[mf][nf], 0, 0, 0);
    }

    // write msg tile to LDS (bf16)
#pragma unroll
    for (int nf = 0; nf < 2; nf++) {
        int edge = eb + nf * 16 + l15;
#pragma unroll
        for (int mf = 0; mf < 4; mf++) {
            int fpos = fb + mf * 16 + lgr * 4;
            f32x4 v = acc[mf][nf];
            uint2 p;
            p.x = pk(v[0], v[1]);
            p.y = pk(v[2], v[3]);
            *(uint2*)(&msg[edge * LDF + fpos]) = p;
        }
    }
    __syncthreads();

    // ---- phase 2: gather + run-length; full segments -> store, else pk atomic
    constexpr int LPF = D / 2;             // threads covering all features
    const int f2   = (t & (LPF - 1)) * 2;  // feature pair
    const int win  = t / LPF;              // window index
    const int base = win * 16;

    unsigned hv[16];
#pragma unroll
    for (int i = 0; i < 16; i++) {
        int src = src_s[base + i];
        hv[i] = *(const unsigned*)(hbf + (size_t)src * D + f2);
    }

    float a0 = 0.f, a1 = 0.f;
    int  cur = dst_x[base + 1];
    bool rs  = (dst_x[base] != cur);       // run starts inside this window?

#pragma unroll
    for (int i = 0; i < 16; ++i) {
        int el = base + i;
        int d  = dst_x[el + 1];
        if (d != cur) {
            if (cur >= 0) {                 // mid-loop flush: run ends here
                unsigned short* ap = agg + (size_t)cur * D + f2;
                unsigned v32 = pk(a0, a1);
                if (rs) {
                    *(unsigned*)ap = v32;   // complete segment: plain store
                } else {
                    asm volatile("global_atomic_pk_add_bf16 %0, %1, off"
                                 :: "v"(ap), "v"(v32) : "memory");
                }
            }
            a0 = 0.f; a1 = 0.f; rs = true; cur = d;
        }
        unsigned pv = *(const unsigned*)(&msg[el * LDF + f2]);
        a0 += fmaxf(bflo(hv[i]) + bflo(pv), 0.f);
        a1 += fmaxf(bfhi(hv[i]) + bfhi(pv), 0.f);
    }
    if (cur >= 0) {
        bool re = (dst_x[base + 17] != cur);   // run ends at window end?
        unsigned short* ap = agg + (size_t)cur * D + f2;
        unsigned v32 = pk(a0, a1);
        if (rs && re) {
            *(unsigned*)ap = v32;
        } else {
            asm volatile("global_atomic_pk_add_bf16 %0, %1, off"
                         :: "v"(ap), "v"(v32) : "memory");
        }
    }
}

// ---------------- W transpose + bf16 convert: W[K,256] f32 -> Wt[256,K] bf16
__global__ __launch_bounds__(THREADS) void wtrans_kernel(
    const float* __restrict__ W, unsigned short* __restrict__ Wt, int K)
{
    __shared__ float tile[32][33];
    const int kb = blockIdx.x * 32, nb = blockIdx.y * 32;
    const int tx = threadIdx.x & 31, ty = threadIdx.x >> 5;
#pragma unroll
    for (int i = ty; i < 32; i += 8)
        tile[i][tx] = W[(size_t)(kb + i) * 256 + nb + tx];
    __syncthreads();
#pragma unroll
    for (int i = ty; i < 32; i += 8)
        Wt[(size_t)(nb + i) * K + kb + tx] = f2bf(tile[tx][i]);
}

// ---------------- MFMA node-MLP GEMM (bf16 in, bf16 out):
// MODE 0: A = (1+eps)*hin + agg(bf16)    MODE 1: A = hin
template<int K, int MODE>
__global__ __launch_bounds__(THREADS) void mfma_mlp_kernel(
    const unsigned short* __restrict__ hin,   // [nrows, K] bf16
    const unsigned short* __restrict__ agg,   // [nrows, K] bf16 (MODE 0)
    const unsigned short* __restrict__ Wt,    // [256, K] bf16
    const float* __restrict__ bias,           // [256]
    const float* __restrict__ epsp,           // [1] (MODE 0)
    unsigned short* __restrict__ out,         // [nrows, 256] bf16
    int nrows)
{
    constexpr int BM = 128, BK = 64;
    constexpr int LDR = BK + 8;
    __shared__ short As[BM * LDR];
    __shared__ short Bs[128 * LDR];

    const int t    = threadIdx.x;
    const int lane = t & 63;
    const int wid  = t >> 6;
    const int wm   = wid >> 1, wn = wid & 1;
    const int l15  = lane & 15, lgr = lane >> 4;

    const int r0 = blockIdx.x * BM;
    const int n0 = blockIdx.y * 128;

    float scale = 1.0f;
    if (MODE == 0) scale = 1.0f + epsp[0];

    f32x4 acc[4][4];
#pragma unroll
    for (int a = 0; a < 4; a++)
#pragma unroll
        for (int b = 0; b < 4; b++) acc[a][b] = (f32x4){0.f, 0.f, 0.f, 0.f};

    for (int k0 = 0; k0 < K; k0 += BK) {
#pragma unroll
        for (int c = 0; c < 4; c++) {
            int idx = t + c * THREADS;
            int r   = idx >> 3;
            int kq  = idx & 7;
            int row = r0 + r;
            uint4 o = make_uint4(0, 0, 0, 0);
            if (row < nrows) {
                size_t g = (size_t)row * K + k0 + kq * 8;
                uint4 hv = *(const uint4*)(hin + g);
                if (MODE == 0) {
                    uint4 av = *(const uint4*)(agg + g);
                    o.x = pk(scale * bflo(hv.x) + bflo(av.x),
                             scale * bfhi(hv.x) + bfhi(av.x));
                    o.y = pk(scale * bflo(hv.y) + bflo(av.y),
                             scale * bfhi(hv.y) + bfhi(av.y));
                    o.z = pk(scale * bflo(hv.z) + bflo(av.z),
                             scale * bfhi(hv.z) + bfhi(av.z));
                    o.w = pk(scale * bflo(hv.w) + bflo(av.w),
                             scale * bfhi(hv.w) + bfhi(av.w));
                } else {
                    o = hv;
                }
            }
            *(uint4*)(&As[r * LDR + kq * 8]) = o;
        }
#pragma unroll
        for (int c = 0; c < 4; c++) {
            int idx = t + c * THREADS;
            int n   = idx >> 3;
            int kq  = idx & 7;
            uint4 w = *(const uint4*)(Wt + (size_t)(n0 + n) * K + k0 + kq * 8);
            *(uint4*)(&Bs[n * LDR + kq * 8]) = w;
        }
        __syncthreads();

#pragma unroll
        for (int ks = 0; ks < 2; ks++) {
            bf16x8 af[4], bfr[4];
#pragma unroll
            for (int mf = 0; mf < 4; mf++)
                af[mf] = *(const bf16x8*)(&As[(wm * 64 + mf * 16 + l15) * LDR + ks * 32 + lgr * 8]);
#pragma unroll
            for (int nf = 0; nf < 4; nf++)
                bfr[nf] = *(const bf16x8*)(&Bs[(wn * 64 + nf * 16 + l15) * LDR + ks * 32 + lgr * 8]);
#pragma unroll
            for (int mf = 0; mf < 4; mf++)
#pragma unroll
                for (int nf = 0; nf < 4; nf++)
                    acc[mf][nf] = __builtin_amdgcn_mfma_f32_16x16x32_bf16(
                        af[mf], bfr[nf], acc[mf][nf], 0, 0, 0);
        }
        __syncthreads();
    }

#pragma unroll
    for (int nf = 0; nf < 4; nf++) {
        int col = n0 + wn * 64 + nf * 16 + l15;
        float bcol = bias[col];
#pragma unroll
        for (int mf = 0; mf < 4; mf++) {
            f32x4 v = acc[mf][nf];
#pragma unroll
            for (int r = 0; r < 4; r++) {
                int row = r0 + wm * 64 + mf * 16 + lgr * 4 + r;
                if (row < nrows)
                    out[(size_t)row * 256 + col] = f2bf(fmaxf(v[r] + bcol, 0.f));
            }
        }
    }
}

// ---------------- global add pool
__global__ __launch_bounds__(THREADS) void pool_kernel(
    const unsigned short* __restrict__ hbf,  // [N, 256] bf16
    const int*   __restrict__ batch,         // [N]
    float*       __restrict__ hg,            // [G, 256] f32
    int nnodes)
{
    constexpr int CH = 64;
    __shared__ int b_s[CH];
    const int t  = threadIdx.x;
    const int v0 = blockIdx.x * CH;
    int cnt = nnodes - v0;
    if (cnt > CH) cnt = CH;
    if (cnt <= 0) return;
    if (t < cnt) b_s[t] = batch[v0 + t];
    __syncthreads();

    int curb  = b_s[0];
    float acc = 0.f;
    for (int v = 0; v < cnt; v++) {
        int b = b_s[v];
        if (b != curb) {
            atomicAdd(&hg[(size_t)curb * 256 + t], acc);
            acc = 0.f; curb = b;
        }
        acc += bf2f(hbf[(size_t)(v0 + v) * 256 + t]);
    }
    atomicAdd(&hg[(size_t)curb * 256 + t], acc);
}

// ---------------- Bayesian weight materialization
__global__ void wprep_kernel(const float* __restrict__ mu,
                             const float* __restrict__ ls,
                             const float* __restrict__ eps,
                             float* __restrict__ w, int n)
{
    int i = blockIdx.x * THREADS + threadIdx.x;
    if (i < n) w[i] = mu[i] + expf(ls[i]) * eps[i];
}

// ---------------- head
__global__ __launch_bounds__(THREADS) void head_kernel(
    const float* __restrict__ hg,
    const float* __restrict__ w1,
    const float* __restrict__ h1_bmu, const float* __restrict__ h1_bls,
    const float* __restrict__ eps_b1,
    const float* __restrict__ h2_wmu, const float* __restrict__ h2_wls,
    const float* __restrict__ eps_w2,
    const float* __restrict__ h2_bmu, const float* __restrict__ h2_bls,
    const float* __restrict__ eps_b2,
    float* __restrict__ out)
{
    __shared__ float x_s[256];
    __shared__ float red[256];
    const int t = threadIdx.x;
    const int g = blockIdx.x;

    x_s[t] = hg[(size_t)g * 256 + t];
    __syncthreads();

    float acc = h1_bmu[t] + expf(h1_bls[t]) * eps_b1[t];
    for (int kk = 0; kk < 256; kk++) acc += x_s[kk] * w1[kk * 256 + t];
    float h1v = acc / (1.f + expf(-acc));

    float w2a = h2_wmu[t * 2 + 0] + expf(h2_wls[t * 2 + 0]) * eps_w2[t * 2 + 0];
    float w2b = h2_wmu[t * 2 + 1] + expf(h2_wls[t * 2 + 1]) * eps_w2[t * 2 + 1];

    red[t] = h1v * w2a;
    __syncthreads();
    for (int s = 128; s > 0; s >>= 1) {
        if (t < s) red[t] += red[t + s];
        __syncthreads();
    }
    if (t == 0) out[(size_t)g * 2 + 0] = red[0] + h2_bmu[0] + expf(h2_bls[0]) * eps_b2[0];
    __syncthreads();

    red[t] = h1v * w2b;
    __syncthreads();
    for (int s = 128; s > 0; s >>= 1) {
        if (t < s) red[t] += red[t + s];
        __syncthreads();
    }
    if (t == 0) out[(size_t)g * 2 + 1] = red[0] + h2_bmu[1] + expf(h2_bls[1]) * eps_b2[1];
}

// ---------------------------------------------------------------------------
extern "C" void kernel_launch(void* const* d_in, const int* in_sizes, int n_in,
                              void* d_out, int out_size, void* d_ws, size_t ws_size,
                              hipStream_t stream)
{
    const float* x         = (const float*)d_in[0];
    const float* edge_attr = (const float*)d_in[1];
    const int*   ei        = (const int*)d_in[2];
    const int*   batch     = (const int*)d_in[3];

    const float* We[3]  = { (const float*)d_in[4],  (const float*)d_in[11], (const float*)d_in[18] };
    const float* be[3]  = { (const float*)d_in[5],  (const float*)d_in[12], (const float*)d_in[19] };
    const float* W1[3]  = { (const float*)d_in[6],  (const float*)d_in[13], (const float*)d_in[20] };
    const float* b1[3]  = { (const float*)d_in[7],  (const float*)d_in[14], (const float*)d_in[21] };
    const float* W2[3]  = { (const float*)d_in[8],  (const float*)d_in[15], (const float*)d_in[22] };
    const float* b2[3]  = { (const float*)d_in[9],  (const float*)d_in[16], (const float*)d_in[23] };
    const float* epsl[3]= { (const float*)d_in[10], (const float*)d_in[17], (const float*)d_in[24] };

    const float* h1_wmu = (const float*)d_in[25];
    const float* h1_wls = (const float*)d_in[26];
    const float* h1_bmu = (const float*)d_in[27];
    const float* h1_bls = (const float*)d_in[28];
    const float* h2_wmu = (const float*)d_in[29];
    const float* h2_wls = (const float*)d_in[30];
    const float* h2_bmu = (const float*)d_in[31];
    const float* h2_bls = (const float*)d_in[32];
    const float* eps_w1 = (const float*)d_in[33];
    const float* eps_b1 = (const float*)d_in[34];
    const float* eps_w2 = (const float*)d_in[35];
    const float* eps_b2 = (const float*)d_in[36];

    const int N = in_sizes[0] / 128;
    const int E = in_sizes[1] / 16;
    const int G = out_size / 2;

    // ---- carve workspace (256B aligned chunks)
    uintptr_t p = (uintptr_t)d_ws;
    auto carve = [&](size_t bytes) -> void* {
        void* r = (void*)p;
        p = (p + bytes + 255) & ~(uintptr_t)255;
        return r;
    };
    float* hg      = (float*)carve((size_t)G * 256 * 4);
    float* w1buf   = (float*)carve(256 * 256 * 4);
    int*   rowptr  = (int*)carve((size_t)(N + 1) * 4);
    int*   cursor  = (int*)carve((size_t)N * 4);
    int*   csr_src = (int*)carve((size_t)E * 4);
    int*   csr_dst = (int*)carve((size_t)E * 4);
    int*   csr_eid = (int*)carve((size_t)E * 4);
    unsigned short* aggbf = (unsigned short*)carve((size_t)N * 256 * 2);
    unsigned short* ea16  = (unsigned short*)carve((size_t)E * 16 * 2);
    unsigned short* hbf   = (unsigned short*)carve((size_t)N * 256 * 2);
    unsigned short* tmpbf = (unsigned short*)carve((size_t)N * 256 * 2);
    unsigned short* xbf   = (unsigned short*)carve((size_t)N * 128 * 2);
    unsigned short* wep[3];
    wep[0] = (unsigned short*)carve(128 * 32 * 2);
    wep[1] = (unsigned short*)carve(256 * 32 * 2);
    wep[2] = (unsigned short*)carve(256 * 32 * 2);
    unsigned short* wt1[3], *wt2[3];
    wt1[0] = (unsigned short*)carve(256 * 128 * 2);
    for (int l = 0; l < 3; l++) {
        if (l) wt1[l] = (unsigned short*)carve(256 * 256 * 2);
        wt2[l] = (unsigned short*)carve(256 * 256 * 2);
    }

    const int eblocks     = (E + THREADS - 1) / THREADS;
    const int pool_blocks = (N + 63) / 64;
    const dim3 ggrid((N + 127) / 128, 2);

    float* out = (float*)d_out;

    // ---- build CSR once
    hipMemsetAsync(cursor, 0, (size_t)N * sizeof(int), stream);
    hist_kernel<<<eblocks, THREADS, 0, stream>>>(ei, cursor, E);
    scan_kernel<<<1, 1024, 0, stream>>>(cursor, rowptr, N);
    hipMemsetAsync(cursor, 0, (size_t)N * sizeof(int), stream);
    fill_kernel<<<eblocks, THREADS, 0, stream>>>(ei, rowptr, cursor, csr_src, csr_dst, csr_eid, E);
    easort_kernel<<<eblocks, THREADS, 0, stream>>>(edge_attr, csr_eid, ea16, E);
    xprep_kernel<<<(N * 32 + THREADS - 1) / THREADS, THREADS, 0, stream>>>(x, xbf, N * 32);

    // ---- weight prep
    wetrans_kernel<<<1, 128, 0, stream>>>(We[0], wep[0], 128);
    wetrans_kernel<<<1, 256, 0, stream>>>(We[1], wep[1], 256);
    wetrans_kernel<<<1, 256, 0, stream>>>(We[2], wep[2], 256);
    wtrans_kernel<<<dim3(4, 8), THREADS, 0, stream>>>(W1[0], wt1[0], 128);
    wtrans_kernel<<<dim3(8, 8), THREADS, 0, stream>>>(W2[0], wt2[0], 256);
    for (int l = 1; l < 3; l++) {
        wtrans_kernel<<<dim3(8, 8), THREADS, 0, stream>>>(W1[l], wt1[l], 256);
        wtrans_kernel<<<dim3(8, 8), THREADS, 0, stream>>>(W2[l], wt2[l], 256);
    }

    // ---- layer 0 (d = 128, h = xbf)
    hipMemsetAsync(aggbf, 0, (size_t)N * 128 * sizeof(unsigned short), stream);
    edge_agg_kernel<128><<<(E + 63) / 64, THREADS, 0, stream>>>(
        xbf, ea16, csr_src, csr_dst, wep[0], be[0], aggbf, E);
    mfma_mlp_kernel<128, 0><<<ggrid, THREADS, 0, stream>>>(
        xbf, aggbf, wt1[0], b1[0], epsl[0], tmpbf, N);
    mfma_mlp_kernel<256, 1><<<ggrid, THREADS, 0, stream>>>(
        tmpbf, nullptr, wt2[0], b2[0], nullptr, hbf, N);

    // ---- layers 1, 2 (d = 256)
    for (int l = 1; l < 3; l++) {
        hipMemsetAsync(aggbf, 0, (size_t)N * 256 * sizeof(unsigned short), stream);
        edge_agg_kernel<256><<<(E + 31) / 32, THREADS, 0, stream>>>(
            hbf, ea16, csr_src, csr_dst, wep[l], be[l], aggbf, E);
        mfma_mlp_kernel<256, 0><<<ggrid, THREADS, 0, stream>>>(
            hbf, aggbf, wt1[l], b1[l], epsl[l], tmpbf, N);
        mfma_mlp_kernel<256, 1><<<ggrid, THREADS, 0, stream>>>(
            tmpbf, nullptr, wt2[l], b2[l], nullptr, hbf, N);
    }

    // ---- global add pool -> hg
    hipMemsetAsync(hg, 0, (size_t)G * 256 * sizeof(float), stream);
    pool_kernel<<<pool_blocks, THREADS, 0, stream>>>(hbf, batch, hg, N);

    // ---- Bayesian head
    wprep_kernel<<<(256 * 256 + THREADS - 1) / THREADS, THREADS, 0, stream>>>(
        h1_wmu, h1_wls, eps_w1, w1buf, 256 * 256);
    head_kernel<<<G, THREADS, 0, stream>>>(
        hg, w1buf, h1_bmu, h1_bls, eps_b1,
        h2_wmu, h2_wls, eps_w2, h2_bmu, h2_bls, eps_b2, out);
}

// Round 10
// 448.776 us; speedup vs baseline: 8.2171x; 1.3174x over previous
//
#include <hip/hip_runtime.h>
#include <hip/hip_bf16.h>
#include <math.h>

// ---------------------------------------------------------------------------
// GINE x3 + global_add_pool + Bayesian head.
// Round 10: per-layer fused MLP kernel (GEMM1 -> relu -> LDS tmp -> GEMM2,
// no tmp global roundtrip); easort fused into fill. edge_agg as in R9.
// ---------------------------------------------------------------------------

#define THREADS 256

typedef __attribute__((ext_vector_type(8))) short bf16x8;
typedef __attribute__((ext_vector_type(4))) float f32x4;

__device__ __forceinline__ unsigned short f2bf(float x) {
    __hip_bfloat16 h = __float2bfloat16(x);
    return __builtin_bit_cast(unsigned short, h);
}
__device__ __forceinline__ float bflo(unsigned u) {
    return __builtin_bit_cast(float, u << 16);
}
__device__ __forceinline__ float bfhi(unsigned u) {
    return __builtin_bit_cast(float, u & 0xffff0000u);
}
__device__ __forceinline__ float bf2f(unsigned short u) {
    return __builtin_bit_cast(float, (unsigned)u << 16);
}
__device__ __forceinline__ unsigned pk(float a, float b) {
    return (unsigned)f2bf(a) | ((unsigned)f2bf(b) << 16);
}

// ---------------- CSR build: histogram of dst
__global__ __launch_bounds__(THREADS) void hist_kernel(
    const int* __restrict__ ei, int* __restrict__ deg, int E)
{
    int e = blockIdx.x * THREADS + threadIdx.x;
    if (e < E) atomicAdd(&deg[ei[E + e]], 1);
}

// ---------------- CSR build: wave-shuffle exclusive scan -> rowptr[0..n]
__global__ __launch_bounds__(1024) void scan_kernel(
    const int* __restrict__ deg, int* __restrict__ rowptr, int n)
{
    __shared__ int wsum[16];
    __shared__ int carry_s;
    const int t    = threadIdx.x;
    const int lane = t & 63, wv = t >> 6;
    if (t == 0) carry_s = 0;
    __syncthreads();
    for (int base = 0; base < n; base += 1024) {
        int i = base + t;
        int incl = (i < n) ? deg[i] : 0;
#pragma unroll
        for (int off = 1; off < 64; off <<= 1) {
            int u = __shfl_up(incl, off, 64);
            if (lane >= off) incl += u;
        }
        if (lane == 63) wsum[wv] = incl;
        __syncthreads();
        if (wv == 0) {
            int s = (lane < 16) ? wsum[lane] : 0;
#pragma unroll
            for (int off = 1; off < 16; off <<= 1) {
                int u = __shfl_up(s, off, 64);
                if (lane >= off) s += u;
            }
            if (lane < 16) wsum[lane] = s;   // inclusive wave sums
        }
        __syncthreads();
        int waveoff = (wv == 0) ? 0 : wsum[wv - 1];
        int carry   = carry_s;
        if (i < n) rowptr[i + 1] = carry + waveoff + incl;
        __syncthreads();
        if (t == 1023) carry_s = carry + wsum[15];
        __syncthreads();
    }
    if (t == 0) rowptr[0] = 0;
}

// ---------------- CSR build: scatter edges into slots + ea16 (fused easort)
__global__ __launch_bounds__(THREADS) void fill_kernel(
    const int* __restrict__ ei, const int* __restrict__ rowptr,
    int* __restrict__ cursor, int* __restrict__ csr_src,
    int* __restrict__ csr_dst, const float* __restrict__ edge_attr,
    unsigned short* __restrict__ ea16, int E)
{
    int e = blockIdx.x * THREADS + threadIdx.x;
    if (e >= E) return;
    int s = ei[e], d = ei[E + e];
    int pos  = atomicAdd(&cursor[d], 1);
    int slot = rowptr[d] + pos;
    csr_src[slot] = s;
    csr_dst[slot] = d;
    const float4* a = (const float4*)(edge_attr + (size_t)e * 16);
    float4 a0 = a[0], a1 = a[1], a2 = a[2], a3 = a[3];
    uint4* dst = (uint4*)(ea16 + (size_t)slot * 16);
    dst[0] = make_uint4(pk(a0.x, a0.y), pk(a0.z, a0.w), pk(a1.x, a1.y), pk(a1.z, a1.w));
    dst[1] = make_uint4(pk(a2.x, a2.y), pk(a2.z, a2.w), pk(a3.x, a3.y), pk(a3.z, a3.w));
}

// ---------------- x -> bf16 copy
__global__ __launch_bounds__(THREADS) void xprep_kernel(
    const float* __restrict__ x, unsigned short* __restrict__ xbf, int n4)
{
    int i = blockIdx.x * THREADS + threadIdx.x;
    if (i >= n4) return;
    float4 v = ((const float4*)x)[i];
    uint2 p;
    p.x = pk(v.x, v.y);
    p.y = pk(v.z, v.w);
    ((uint2*)xbf)[i] = p;
}

// ---------------- We[16][D] f32 -> Wtp[D][32] bf16 (k 16..31 zero)
__global__ __launch_bounds__(THREADS) void wetrans_kernel(
    const float* __restrict__ We, unsigned short* __restrict__ Wtp, int D)
{
    int f = blockIdx.x * THREADS + threadIdx.x;
    if (f >= D) return;
#pragma unroll
    for (int k = 0; k < 16; k++) Wtp[f * 32 + k] = f2bf(We[k * D + f]);
#pragma unroll
    for (int k = 16; k < 32; k++) Wtp[f * 32 + k] = 0;
}

// ---------------- fused MFMA aggregation (as R9):
// phase1: msg[f][e] = ea[e][:16] @ We[:,f] + be[f]  (MFMA, bias in C-init)
// phase2: agg[dst][f] += relu(h[src][f] + msg)  -> bf16 agg, packed atomics;
//         full-in-window segments use a plain store (no RMW).
template<int D>
__global__ __launch_bounds__(THREADS) void edge_agg_kernel(
    const unsigned short* __restrict__ hbf,   // [N][D] bf16
    const unsigned short* __restrict__ ea16,  // [E][16] bf16, CSR order
    const int* __restrict__ csr_src,          // [E]
    const int* __restrict__ csr_dst,          // [E] (non-decreasing)
    const unsigned short* __restrict__ Wtp,   // [D][32] bf16, k>=16 zero
    const float* __restrict__ be,             // [D]
    unsigned short* __restrict__ agg,         // [N][D] bf16, pre-zeroed
    int E)
{
    constexpr int EPB = (D == 128) ? 64 : 32;    // edges per block
    constexpr int LDF = D + 8;                   // padded LDS stride (shorts)
    __shared__ unsigned short msg[EPB * LDF];
    __shared__ int src_s[EPB];
    __shared__ int dst_x[EPB + 2];               // dst of edges e0-1 .. e0+EPB

    const int t    = threadIdx.x;
    const int e0   = blockIdx.x * EPB;
    const int lane = t & 63, wid = t >> 6;
    const int l15  = lane & 15, lgr = lane >> 4;

    for (int i = t; i < EPB; i += THREADS) {
        int e = e0 + i;
        src_s[i] = (e < E) ? csr_src[e] : 0;
    }
    for (int i = t; i < EPB + 2; i += THREADS) {
        int e = e0 + i - 1;
        dst_x[i] = (e < 0) ? -2 : ((e < E) ? csr_dst[e] : -1);
    }

    const int fb = (D == 128) ? (wid & 1) * 64 : wid * 64;   // feature base
    const int eb = (D == 128) ? (wid >> 1) * 32 : 0;         // edge base

    bf16x8 af[4];
#pragma unroll
    for (int mf = 0; mf < 4; mf++)
        af[mf] = *(const bf16x8*)(Wtp + (size_t)(fb + mf * 16 + l15) * 32 + lgr * 8);

    f32x4 acc[4][2];
#pragma unroll
    for (int mf = 0; mf < 4; mf++) {
        int fpos = fb + mf * 16 + lgr * 4;
        float4 bv4 = *(const float4*)(be + fpos);
        f32x4 binit = (f32x4){bv4.x, bv4.y, bv4.z, bv4.w};
        acc[mf][0] = binit;
        acc[mf][1] = binit;
    }

#pragma unroll
    for (int nf = 0; nf < 2; nf++) {
        int er = e0 + eb + nf * 16 + l15;
        bf16x8 bv = (bf16x8){0, 0, 0, 0, 0, 0, 0, 0};
        if (lgr < 2 && er < E)
            bv = *(const bf16x8*)(ea16 + (size_t)er * 16 + lgr * 8);
#pragma unroll
        for (int mf = 0; mf < 4; mf++)
            acc[mf][nf] = __builtin_amdgcn_mfma_f32_16x16x32_bf16(
                af[mf], bv, acc[mf][nf], 0, 0, 0);
    }

#pragma unroll
    for (int nf = 0; nf < 2; nf++) {
        int edge = eb + nf * 16 + l15;
#pragma unroll
        for (int mf = 0; mf < 4; mf++) {
            int fpos = fb + mf * 16 + lgr * 4;
            f32x4 v = acc[mf][nf];
            uint2 p;
            p.x = pk(v[0], v[1]);
            p.y = pk(v[2], v[3]);
            *(uint2*)(&msg[edge * LDF + fpos]) = p;
        }
    }
    __syncthreads();

    constexpr int LPF = D / 2;
    const int f2   = (t & (LPF - 1)) * 2;
    const int win  = t / LPF;
    const int base = win * 16;

    unsigned hv[16];
#pragma unroll
    for (int i = 0; i < 16; i++) {
        int src = src_s[base + i];
        hv[i] = *(const unsigned*)(hbf + (size_t)src * D + f2);
    }

    float a0 = 0.f, a1 = 0.f;
    int  cur = dst_x[base + 1];
    bool rs  = (dst_x[base] != cur);

#pragma unroll
    for (int i = 0; i < 16; ++i) {
        int el = base + i;
        int d  = dst_x[el + 1];
        if (d != cur) {
            if (cur >= 0) {
                unsigned short* ap = agg + (size_t)cur * D + f2;
                unsigned v32 = pk(a0, a1);
                if (rs) {
                    *(unsigned*)ap = v32;
                } else {
                    asm volatile("global_atomic_pk_add_bf16 %0, %1, off"
                                 :: "v"(ap), "v"(v32) : "memory");
                }
            }
            a0 = 0.f; a1 = 0.f; rs = true; cur = d;
        }
        unsigned pv = *(const unsigned*)(&msg[el * LDF + f2]);
        a0 += fmaxf(bflo(hv[i]) + bflo(pv), 0.f);
        a1 += fmaxf(bfhi(hv[i]) + bfhi(pv), 0.f);
    }
    if (cur >= 0) {
        bool re = (dst_x[base + 17] != cur);
        unsigned short* ap = agg + (size_t)cur * D + f2;
        unsigned v32 = pk(a0, a1);
        if (rs && re) {
            *(unsigned*)ap = v32;
        } else {
            asm volatile("global_atomic_pk_add_bf16 %0, %1, off"
                         :: "v"(ap), "v"(v32) : "memory");
        }
    }
}

// ---------------- W transpose + bf16 convert: W[K,256] f32 -> Wt[256,K] bf16
__global__ __launch_bounds__(THREADS) void wtrans_kernel(
    const float* __restrict__ W, unsigned short* __restrict__ Wt, int K)
{
    __shared__ float tile[32][33];
    const int kb = blockIdx.x * 32, nb = blockIdx.y * 32;
    const int tx = threadIdx.x & 31, ty = threadIdx.x >> 5;
#pragma unroll
    for (int i = ty; i < 32; i += 8)
        tile[i][tx] = W[(size_t)(kb + i) * 256 + nb + tx];
    __syncthreads();
#pragma unroll
    for (int i = ty; i < 32; i += 8)
        Wt[(size_t)(nb + i) * K + kb + tx] = f2bf(tile[tx][i]);
}

// ---------------- fused node MLP (both GEMMs, tmp in LDS):
// z   = relu( ((1+eps)*hin + agg) @ Wt1^T + b1 )   (KIN -> 256)
// out = relu( z @ Wt2^T + b2 )                     (256 -> 256)
// Block: 64 rows x 256 cols; 4 waves, wave w owns cols [w*64, w*64+64).
template<int KIN>
__global__ __launch_bounds__(THREADS) void fused_mlp_kernel(
    const unsigned short* __restrict__ hin,   // [nrows, KIN] bf16
    const unsigned short* __restrict__ agg,   // [nrows, KIN] bf16
    const unsigned short* __restrict__ Wt1,   // [256, KIN] bf16
    const float* __restrict__ b1,             // [256]
    const unsigned short* __restrict__ Wt2,   // [256, 256] bf16
    const float* __restrict__ b2,             // [256]
    const float* __restrict__ epsp,           // [1]
    unsigned short* __restrict__ out,         // [nrows, 256] bf16
    int nrows)
{
    constexpr int LDR = 72;                   // 64 + 8 shorts
    constexpr int LDT = 264;                  // 256 + 8 shorts
    __shared__ short As[64 * LDR];            //  9.2 KB
    __shared__ short Bs[256 * LDR];           // 36.9 KB
    __shared__ short Tmp[64 * LDT];           // 33.8 KB

    const int t    = threadIdx.x;
    const int lane = t & 63;
    const int wid  = t >> 6;                  // wave col-stripe
    const int l15  = lane & 15, lgr = lane >> 4;
    const int r0   = blockIdx.x * 64;

    const float scale = 1.0f + epsp[0];

    f32x4 acc[4][4];
    // ---- GEMM1 accumulator init with b1 (bias via C-init)
#pragma unroll
    for (int nf = 0; nf < 4; nf++) {
        float bv = b1[wid * 64 + nf * 16 + l15];
#pragma unroll
        for (int mf = 0; mf < 4; mf++)
            acc[mf][nf] = (f32x4){bv, bv, bv, bv};
    }

    for (int k0 = 0; k0 < KIN; k0 += 64) {
        // stage A: 64 rows x 64 k (2 x 16B per thread), fused (1+eps)h + agg
#pragma unroll
        for (int c = 0; c < 2; c++) {
            int idx = t + c * THREADS;        // 0..511
            int r   = idx >> 3;               // 0..63
            int kq  = idx & 7;
            int row = r0 + r;
            uint4 o = make_uint4(0, 0, 0, 0);
            if (row < nrows) {
                size_t g = (size_t)row * KIN + k0 + kq * 8;
                uint4 hv = *(const uint4*)(hin + g);
                uint4 av = *(const uint4*)(agg + g);
                o.x = pk(scale * bflo(hv.x) + bflo(av.x),
                         scale * bfhi(hv.x) + bfhi(av.x));
                o.y = pk(scale * bflo(hv.y) + bflo(av.y),
                         scale * bfhi(hv.y) + bfhi(av.y));
                o.z = pk(scale * bflo(hv.z) + bflo(av.z),
                         scale * bfhi(hv.z) + bfhi(av.z));
                o.w = pk(scale * bflo(hv.w) + bflo(av.w),
                         scale * bfhi(hv.w) + bfhi(av.w));
            }
            *(uint4*)(&As[r * LDR + kq * 8]) = o;
        }
        // stage B1: 256 n x 64 k (8 x 16B per thread)
#pragma unroll
        for (int c = 0; c < 8; c++) {
            int idx = t + c * THREADS;        // 0..2047
            int n   = idx >> 3;
            int kq  = idx & 7;
            uint4 w = *(const uint4*)(Wt1 + (size_t)n * KIN + k0 + kq * 8);
            *(uint4*)(&Bs[n * LDR + kq * 8]) = w;
        }
        __syncthreads();

#pragma unroll
        for (int ks = 0; ks < 2; ks++) {
            bf16x8 afr[4], bfr[4];
#pragma unroll
            for (int mf = 0; mf < 4; mf++)
                afr[mf] = *(const bf16x8*)(&As[(mf * 16 + l15) * LDR + ks * 32 + lgr * 8]);
#pragma unroll
            for (int nf = 0; nf < 4; nf++)
                bfr[nf] = *(const bf16x8*)(&Bs[(wid * 64 + nf * 16 + l15) * LDR + ks * 32 + lgr * 8]);
#pragma unroll
            for (int mf = 0; mf < 4; mf++)
#pragma unroll
                for (int nf = 0; nf < 4; nf++)
                    acc[mf][nf] = __builtin_amdgcn_mfma_f32_16x16x32_bf16(
                        afr[mf], bfr[nf], acc[mf][nf], 0, 0, 0);
        }
        __syncthreads();
    }

    // ---- relu + write z to Tmp (bf16), then re-init acc with b2
#pragma unroll
    for (int nf = 0; nf < 4; nf++) {
        int col = wid * 64 + nf * 16 + l15;
#pragma unroll
        for (int mf = 0; mf < 4; mf++) {
            f32x4 v = acc[mf][nf];
#pragma unroll
            for (int r = 0; r < 4; r++) {
                int row = mf * 16 + lgr * 4 + r;
                Tmp[row * LDT + col] = (short)f2bf(fmaxf(v[r], 0.f));
            }
        }
    }
#pragma unroll
    for (int nf = 0; nf < 4; nf++) {
        float bv = b2[wid * 64 + nf * 16 + l15];
#pragma unroll
        for (int mf = 0; mf < 4; mf++)
            acc[mf][nf] = (f32x4){bv, bv, bv, bv};
    }
    __syncthreads();

    // ---- GEMM2: A = Tmp (K=256), B = Wt2
    for (int k0 = 0; k0 < 256; k0 += 64) {
#pragma unroll
        for (int c = 0; c < 8; c++) {
            int idx = t + c * THREADS;
            int n   = idx >> 3;
            int kq  = idx & 7;
            uint4 w = *(const uint4*)(Wt2 + (size_t)n * 256 + k0 + kq * 8);
            *(uint4*)(&Bs[n * LDR + kq * 8]) = w;
        }
        __syncthreads();

#pragma unroll
        for (int ks = 0; ks < 2; ks++) {
            bf16x8 afr[4], bfr[4];
#pragma unroll
            for (int mf = 0; mf < 4; mf++)
                afr[mf] = *(const bf16x8*)(&Tmp[(mf * 16 + l15) * LDT + k0 + ks * 32 + lgr * 8]);
#pragma unroll
            for (int nf = 0; nf < 4; nf++)
                bfr[nf] = *(const bf16x8*)(&Bs[(wid * 64 + nf * 16 + l15) * LDR + ks * 32 + lgr * 8]);
#pragma unroll
            for (int mf = 0; mf < 4; mf++)
#pragma unroll
                for (int nf = 0; nf < 4; nf++)
                    acc[mf][nf] = __builtin_amdgcn_mfma_f32_16x16x32_bf16(
                        afr[mf], bfr[nf], acc[mf][nf], 0, 0, 0);
        }
        __syncthreads();
    }

    // ---- epilogue: relu, bf16 store
#pragma unroll
    for (int nf = 0; nf < 4; nf++) {
        int col = wid * 64 + nf * 16 + l15;
#pragma unroll
        for (int mf = 0; mf < 4; mf++) {
            f32x4 v = acc[mf][nf];
#pragma unroll
            for (int r = 0; r < 4; r++) {
                int row = r0 + mf * 16 + lgr * 4 + r;
                if (row < nrows)
                    out[(size_t)row * 256 + col] = f2bf(fmaxf(v[r], 0.f));
            }
        }
    }
}

// ---------------- global add pool
__global__ __launch_bounds__(THREADS) void pool_kernel(
    const unsigned short* __restrict__ hbf,  // [N, 256] bf16
    const int*   __restrict__ batch,         // [N]
    float*       __restrict__ hg,            // [G, 256] f32
    int nnodes)
{
    constexpr int CH = 64;
    __shared__ int b_s[CH];
    const int t  = threadIdx.x;
    const int v0 = blockIdx.x * CH;
    int cnt = nnodes - v0;
    if (cnt > CH) cnt = CH;
    if (cnt <= 0) return;
    if (t < cnt) b_s[t] = batch[v0 + t];
    __syncthreads();

    int curb  = b_s[0];
    float acc = 0.f;
    for (int v = 0; v < cnt; v++) {
        int b = b_s[v];
        if (b != curb) {
            atomicAdd(&hg[(size_t)curb * 256 + t], acc);
            acc = 0.f; curb = b;
        }
        acc += bf2f(hbf[(size_t)(v0 + v) * 256 + t]);
    }
    atomicAdd(&hg[(size_t)curb * 256 + t], acc);
}

// ---------------- Bayesian weight materialization
__global__ void wprep_kernel(const float* __restrict__ mu,
                             const float* __restrict__ ls,
                             const float* __restrict__ eps,
                             float* __restrict__ w, int n)
{
    int i = blockIdx.x * THREADS + threadIdx.x;
    if (i < n) w[i] = mu[i] + expf(ls[i]) * eps[i];
}

// ---------------- head
__global__ __launch_bounds__(THREADS) void head_kernel(
    const float* __restrict__ hg,
    const float* __restrict__ w1,
    const float* __restrict__ h1_bmu, const float* __restrict__ h1_bls,
    const float* __restrict__ eps_b1,
    const float* __restrict__ h2_wmu, const float* __restrict__ h2_wls,
    const float* __restrict__ eps_w2,
    const float* __restrict__ h2_bmu, const float* __restrict__ h2_bls,
    const float* __restrict__ eps_b2,
    float* __restrict__ out)
{
    __shared__ float x_s[256];
    __shared__ float red[256];
    const int t = threadIdx.x;
    const int g = blockIdx.x;

    x_s[t] = hg[(size_t)g * 256 + t];
    __syncthreads();

    float acc = h1_bmu[t] + expf(h1_bls[t]) * eps_b1[t];
    for (int kk = 0; kk < 256; kk++) acc += x_s[kk] * w1[kk * 256 + t];
    float h1v = acc / (1.f + expf(-acc));

    float w2a = h2_wmu[t * 2 + 0] + expf(h2_wls[t * 2 + 0]) * eps_w2[t * 2 + 0];
    float w2b = h2_wmu[t * 2 + 1] + expf(h2_wls[t * 2 + 1]) * eps_w2[t * 2 + 1];

    red[t] = h1v * w2a;
    __syncthreads();
    for (int s = 128; s > 0; s >>= 1) {
        if (t < s) red[t] += red[t + s];
        __syncthreads();
    }
    if (t == 0) out[(size_t)g * 2 + 0] = red[0] + h2_bmu[0] + expf(h2_bls[0]) * eps_b2[0];
    __syncthreads();

    red[t] = h1v * w2b;
    __syncthreads();
    for (int s = 128; s > 0; s >>= 1) {
        if (t < s) red[t] += red[t + s];
        __syncthreads();
    }
    if (t == 0) out[(size_t)g * 2 + 1] = red[0] + h2_bmu[1] + expf(h2_bls[1]) * eps_b2[1];
}

// ---------------------------------------------------------------------------
extern "C" void kernel_launch(void* const* d_in, const int* in_sizes, int n_in,
                              void* d_out, int out_size, void* d_ws, size_t ws_size,
                              hipStream_t stream)
{
    const float* x         = (const float*)d_in[0];
    const float* edge_attr = (const float*)d_in[1];
    const int*   ei        = (const int*)d_in[2];
    const int*   batch     = (const int*)d_in[3];

    const float* We[3]  = { (const float*)d_in[4],  (const float*)d_in[11], (const float*)d_in[18] };
    const float* be[3]  = { (const float*)d_in[5],  (const float*)d_in[12], (const float*)d_in[19] };
    const float* W1[3]  = { (const float*)d_in[6],  (const float*)d_in[13], (const float*)d_in[20] };
    const float* b1[3]  = { (const float*)d_in[7],  (const float*)d_in[14], (const float*)d_in[21] };
    const float* W2[3]  = { (const float*)d_in[8],  (const float*)d_in[15], (const float*)d_in[22] };
    const float* b2[3]  = { (const float*)d_in[9],  (const float*)d_in[16], (const float*)d_in[23] };
    const float* epsl[3]= { (const float*)d_in[10], (const float*)d_in[17], (const float*)d_in[24] };

    const float* h1_wmu = (const float*)d_in[25];
    const float* h1_wls = (const float*)d_in[26];
    const float* h1_bmu = (const float*)d_in[27];
    const float* h1_bls = (const float*)d_in[28];
    const float* h2_wmu = (const float*)d_in[29];
    const float* h2_wls = (const float*)d_in[30];
    const float* h2_bmu = (const float*)d_in[31];
    const float* h2_bls = (const float*)d_in[32];
    const float* eps_w1 = (const float*)d_in[33];
    const float* eps_b1 = (const float*)d_in[34];
    const float* eps_w2 = (const float*)d_in[35];
    const float* eps_b2 = (const float*)d_in[36];

    const int N = in_sizes[0] / 128;
    const int E = in_sizes[1] / 16;
    const int G = out_size / 2;

    // ---- carve workspace (256B aligned chunks)
    uintptr_t p = (uintptr_t)d_ws;
    auto carve = [&](size_t bytes) -> void* {
        void* r = (void*)p;
        p = (p + bytes + 255) & ~(uintptr_t)255;
        return r;
    };
    float* hg      = (float*)carve((size_t)G * 256 * 4);
    float* w1buf   = (float*)carve(256 * 256 * 4);
    int*   rowptr  = (int*)carve((size_t)(N + 1) * 4);
    int*   cursor  = (int*)carve((size_t)N * 4);
    int*   csr_src = (int*)carve((size_t)E * 4);
    int*   csr_dst = (int*)carve((size_t)E * 4);
    unsigned short* aggbf = (unsigned short*)carve((size_t)N * 256 * 2);
    unsigned short* ea16  = (unsigned short*)carve((size_t)E * 16 * 2);
    unsigned short* hbf   = (unsigned short*)carve((size_t)N * 256 * 2);
    unsigned short* xbf   = (unsigned short*)carve((size_t)N * 128 * 2);
    unsigned short* wep[3];
    wep[0] = (unsigned short*)carve(128 * 32 * 2);
    wep[1] = (unsigned short*)carve(256 * 32 * 2);
    wep[2] = (unsigned short*)carve(256 * 32 * 2);
    unsigned short* wt1[3], *wt2[3];
    wt1[0] = (unsigned short*)carve(256 * 128 * 2);
    for (int l = 0; l < 3; l++) {
        if (l) wt1[l] = (unsigned short*)carve(256 * 256 * 2);
        wt2[l] = (unsigned short*)carve(256 * 256 * 2);
    }

    const int eblocks     = (E + THREADS - 1) / THREADS;
    const int pool_blocks = (N + 63) / 64;
    const int mlp_blocks  = (N + 63) / 64;

    float* out = (float*)d_out;

    // ---- build CSR once (fill also sorts edge_attr -> ea16)
    hipMemsetAsync(cursor, 0, (size_t)N * sizeof(int), stream);
    hist_kernel<<<eblocks, THREADS, 0, stream>>>(ei, cursor, E);
    scan_kernel<<<1, 1024, 0, stream>>>(cursor, rowptr, N);
    hipMemsetAsync(cursor, 0, (size_t)N * sizeof(int), stream);
    fill_kernel<<<eblocks, THREADS, 0, stream>>>(
        ei, rowptr, cursor, csr_src, csr_dst, edge_attr, ea16, E);
    xprep_kernel<<<(N * 32 + THREADS - 1) / THREADS, THREADS, 0, stream>>>(x, xbf, N * 32);

    // ---- weight prep
    wetrans_kernel<<<1, 128, 0, stream>>>(We[0], wep[0], 128);
    wetrans_kernel<<<1, 256, 0, stream>>>(We[1], wep[1], 256);
    wetrans_kernel<<<1, 256, 0, stream>>>(We[2], wep[2], 256);
    wtrans_kernel<<<dim3(4, 8), THREADS, 0, stream>>>(W1[0], wt1[0], 128);
    wtrans_kernel<<<dim3(8, 8), THREADS, 0, stream>>>(W2[0], wt2[0], 256);
    for (int l = 1; l < 3; l++) {
        wtrans_kernel<<<dim3(8, 8), THREADS, 0, stream>>>(W1[l], wt1[l], 256);
        wtrans_kernel<<<dim3(8, 8), THREADS, 0, stream>>>(W2[l], wt2[l], 256);
    }

    // ---- layer 0 (d = 128, h = xbf)
    hipMemsetAsync(aggbf, 0, (size_t)N * 128 * sizeof(unsigned short), stream);
    edge_agg_kernel<128><<<(E + 63) / 64, THREADS, 0, stream>>>(
        xbf, ea16, csr_src, csr_dst, wep[0], be[0], aggbf, E);
    fused_mlp_kernel<128><<<mlp_blocks, THREADS, 0, stream>>>(
        xbf, aggbf, wt1[0], b1[0], wt2[0], b2[0], epsl[0], hbf, N);

    // ---- layers 1, 2 (d = 256)
    for (int l = 1; l < 3; l++) {
        hipMemsetAsync(aggbf, 0, (size_t)N * 256 * sizeof(unsigned short), stream);
        edge_agg_kernel<256><<<(E + 31) / 32, THREADS, 0, stream>>>(
            hbf, ea16, csr_src, csr_dst, wep[l], be[l], aggbf, E);
        fused_mlp_kernel<256><<<mlp_blocks, THREADS, 0, stream>>>(
            hbf, aggbf, wt1[l], b1[l], wt2[l], b2[l], epsl[l], hbf, N);
    }

    // ---- global add pool -> hg
    hipMemsetAsync(hg, 0, (size_t)G * 256 * sizeof(float), stream);
    pool_kernel<<<pool_blocks, THREADS, 0, stream>>>(hbf, batch, hg, N);

    // ---- Bayesian head
    wprep_kernel<<<(256 * 256 + THREADS - 1) / THREADS, THREADS, 0, stream>>>(
        h1_wmu, h1_wls, eps_w1, w1buf, 256 * 256);
    head_kernel<<<G, THREADS, 0, stream>>>(
        hg, w1buf, h1_bmu, h1_bls, eps_b1,
        h2_wmu, h2_wls, eps_w2, h2_bmu, h2_bls, eps_b2, out);
}